// Round 5
// baseline (433.039 us; speedup 1.0000x reference)
//
#include <hip/hip_runtime.h>
#include <math.h>

#define Bc 4
#define Lc 512
#define Dc 768
#define Hc 12
#define Mc 48
#define Ec 32
#define Pc 512
#define Rc 97
#define MINV 1e-30f

typedef _Float16 f16;
typedef __attribute__((ext_vector_type(8))) _Float16 f16x8;
typedef __attribute__((ext_vector_type(16))) float f32x16;

// ---------------- K0: fused fp32 -> f16 convert for 4 DxD weights ----------------
__global__ __launch_bounds__(256) void k_cvt4(const float* __restrict__ s0, const float* __restrict__ s1,
                                              const float* __restrict__ s2, const float* __restrict__ s3,
                                              f16* __restrict__ d0, f16* __restrict__ d1,
                                              f16* __restrict__ d2, f16* __restrict__ d3) {
    const int DD = Dc * Dc;
    int i = blockIdx.x * 256 + threadIdx.x;
    int stride = gridDim.x * 256;
    for (; i < 4 * DD; i += stride) {
        int sel = i / DD, j = i % DD;
        const float* s = (sel == 0) ? s0 : (sel == 1) ? s1 : (sel == 2) ? s2 : s3;
        f16* d = (sel == 0) ? d0 : (sel == 1) ? d1 : (sel == 2) ? d2 : d3;
        d[j] = (f16)s[j];
    }
}

// ---------------- K0b: transpose context -> ctxT[b][d][l] f16 ----------------
__global__ __launch_bounds__(256) void k_tran(const float* __restrict__ ctx, f16* __restrict__ ctxT) {
    int id = blockIdx.x;           // ((b*8+lt)*12+dt)
    int dt = id % 12; int lt = (id / 12) % 8; int b = id / 96;
    int l0 = lt * 64, d0 = dt * 64;
    __shared__ f16 Ts[64][72];
    int tid = threadIdx.x;
    int r = tid >> 2, cg = tid & 3;
    const float* src = ctx + ((size_t)b * Lc + l0 + r) * Dc + d0 + cg * 16;
#pragma unroll
    for (int u = 0; u < 4; ++u) {
        float4 v = ((const float4*)src)[u];
        Ts[cg * 16 + u * 4 + 0][r] = (f16)v.x;
        Ts[cg * 16 + u * 4 + 1][r] = (f16)v.y;
        Ts[cg * 16 + u * 4 + 2][r] = (f16)v.z;
        Ts[cg * 16 + u * 4 + 3][r] = (f16)v.w;
    }
    __syncthreads();
    int dr = tid >> 2, seg = tid & 3;
    f16* dst = ctxT + ((size_t)b * Dc + d0 + dr) * Lc + l0 + seg * 16;
    f16x8 o0, o1;
#pragma unroll
    for (int j = 0; j < 8; ++j) { o0[j] = Ts[dr][seg * 16 + j]; o1[j] = Ts[dr][seg * 16 + 8 + j]; }
    *(f16x8*)dst = o0;
    *(f16x8*)(dst + 8) = o1;
}

// ---------------- K1 v2: mention = mm @ ctx via MFMA (M=48 pad 64, N=64 tiles, K=512) ----------------
__global__ __launch_bounds__(256) void k_mention_mfma(const float* __restrict__ mm,
                                                      const f16* __restrict__ ctxT,
                                                      float* __restrict__ mention) {
    __shared__ __align__(16) f16 As[2][64 * 64];
    __shared__ __align__(16) f16 Bs[2][64 * 64];
    int id = blockIdx.x;            // b*12+dt
    int dt = id % 12; int b = id / 12;
    int d0 = dt * 64;
    int tid = threadIdx.x;
    int w = tid >> 6, lane = tid & 63;
    int w_m = w & 1, w_n = w >> 1;
    int m_l = lane & 31, kg = lane >> 5;
    int r0 = tid >> 3, cc0 = tid & 7;
    int r1 = r0 + 32;
    int mr0 = (r0 < Mc) ? r0 : r0 - Mc;   // junk rows read valid addresses
    int mr1 = (r1 < Mc) ? r1 : r1 - Mc;
    f16x8 ar0, ar1, br0, br1;
    auto loadt = [&](int it) {
        int k0 = it * 64;
        const float* A0 = mm + ((size_t)b * Mc + mr0) * Lc + k0 + cc0 * 8;
        const float* A1 = mm + ((size_t)b * Mc + mr1) * Lc + k0 + cc0 * 8;
#pragma unroll
        for (int j = 0; j < 8; ++j) { ar0[j] = (f16)A0[j]; ar1[j] = (f16)A1[j]; }
        br0 = *(const f16x8*)(ctxT + ((size_t)b * Dc + d0 + r0) * Lc + k0 + cc0 * 8);
        br1 = *(const f16x8*)(ctxT + ((size_t)b * Dc + d0 + r1) * Lc + k0 + cc0 * 8);
    };
    auto writet = [&](int p) {
        ((f16x8*)As[p])[r0 * 8 + (cc0 ^ (r0 & 7))] = ar0;
        ((f16x8*)As[p])[r1 * 8 + (cc0 ^ (r1 & 7))] = ar1;
        ((f16x8*)Bs[p])[r0 * 8 + (cc0 ^ (r0 & 7))] = br0;
        ((f16x8*)Bs[p])[r1 * 8 + (cc0 ^ (r1 & 7))] = br1;
    };
    loadt(0); writet(0); loadt(1);
    f32x16 acc;
#pragma unroll
    for (int i = 0; i < 16; ++i) acc[i] = 0.f;
    int ar = w_m * 32 + m_l;
    int br = w_n * 32 + m_l;
    for (int it = 0; it < 8; ++it) {
        int p = it & 1;
        __syncthreads();
        if (it < 7) writet(p ^ 1);
        if (it < 6) loadt(it + 2);
#pragma unroll
        for (int s = 0; s < 4; ++s) {
            int ck = s * 2 + kg;
            f16x8 a = ((const f16x8*)As[p])[ar * 8 + (ck ^ (ar & 7))];
            f16x8 bv = ((const f16x8*)Bs[p])[br * 8 + (ck ^ (br & 7))];
            acc = __builtin_amdgcn_mfma_f32_32x32x16_f16(a, bv, acc, 0, 0, 0);
        }
    }
#pragma unroll
    for (int reg = 0; reg < 16; ++reg) {
        int row = (reg & 3) + 8 * (reg >> 2) + 4 * kg;
        int m = w_m * 32 + row;
        if (m < Mc) mention[((size_t)b * Mc + m) * Dc + d0 + w_n * 32 + m_l] = acc[reg];
    }
}

// ---------------- K2 fused: one pass over attention ----------------
// Per (b,h,mt): P = [mm_b(48); emt_b(32); 0(16)] (96x512) @ att[b,h][:, m0:m0+64]
// rows<48 -> atomicAdd tmpML (sum over h); rows 48..79 -> eat.
__global__ __launch_bounds__(256) void k_attpass(const float* __restrict__ mm,
                                                 const float* __restrict__ emt,
                                                 const float* __restrict__ att,
                                                 float* __restrict__ tmpML,
                                                 float* __restrict__ eat) {
    __shared__ __align__(16) f16 Ss[96 * 64];     // [row][8 chunks ^(row&7)][8]
    __shared__ __align__(16) f16 attS[64 * 64];   // [m][8 chunks ^(m&7)][8]
    int id = blockIdx.x;
    int mt = id & 7; int bh = id >> 3;
    int b = bh / Hc, h = bh % Hc;
    int m0 = mt * 64;
    int tid = threadIdx.x;
    int w = tid >> 6, lane = tid & 63;
    int n_l = lane & 31, kg = lane >> 5;

    const float* ab = att + (size_t)bh * Lc * Lc + m0;
    int mRow = tid & 63, lg = tid >> 6;   // lg: l-quarter (16 l each)
    float pre[16];
#pragma unroll
    for (int q = 0; q < 16; ++q) pre[q] = ab[(size_t)(lg * 16 + q) * Lc + mRow];

    f32x16 acc[2];
#pragma unroll
    for (int nt = 0; nt < 2; ++nt)
#pragma unroll
        for (int i = 0; i < 16; ++i) acc[nt][i] = 0.f;

    for (int kc = 0; kc < 8; ++kc) {
        __syncthreads();
        // stage attention tile (transposed) f16
#pragma unroll
        for (int half = 0; half < 2; ++half) {
            int cc = lg * 2 + half;
            f16x8 v;
#pragma unroll
            for (int jj = 0; jj < 8; ++jj) v[jj] = (f16)pre[half * 8 + jj];
            ((f16x8*)attS)[mRow * 8 + (cc ^ (mRow & 7))] = v;
        }
        // stage stacked A rows f16: 96 rows x 8 chunks = 768, 3 per thread
#pragma unroll
        for (int k = 0; k < 3; ++k) {
            int idx = tid + k * 256;
            int row = idx >> 3, cc = idx & 7;
            f16x8 v;
            if (row < Mc) {
                const float* src = mm + ((size_t)b * Mc + row) * Lc + kc * 64 + cc * 8;
#pragma unroll
                for (int j = 0; j < 8; ++j) v[j] = (f16)src[j];
            } else if (row < 80) {
                const float* src = emt + ((size_t)b * Ec + row - Mc) * Lc + kc * 64 + cc * 8;
#pragma unroll
                for (int j = 0; j < 8; ++j) v[j] = (f16)src[j];
            } else {
#pragma unroll
                for (int j = 0; j < 8; ++j) v[j] = (f16)0.f;
            }
            ((f16x8*)Ss)[row * 8 + (cc ^ (row & 7))] = v;
        }
        if (kc < 7) {
#pragma unroll
            for (int q = 0; q < 16; ++q)
                pre[q] = ab[(size_t)((kc + 1) * 64 + lg * 16 + q) * Lc + mRow];
        }
        __syncthreads();
        if (w < 3) {
            int arow = w * 32 + n_l;
#pragma unroll
            for (int kk = 0; kk < 4; ++kk) {
                int cc = kk * 2 + kg;
                f16x8 a = ((const f16x8*)Ss)[arow * 8 + (cc ^ (arow & 7))];
#pragma unroll
                for (int nt = 0; nt < 2; ++nt) {
                    int bcol = nt * 32 + n_l;
                    f16x8 bb = ((const f16x8*)attS)[bcol * 8 + (cc ^ (bcol & 7))];
                    acc[nt] = __builtin_amdgcn_mfma_f32_32x32x16_f16(a, bb, acc[nt], 0, 0, 0);
                }
            }
        }
    }
    if (w < 3) {
#pragma unroll
        for (int nt = 0; nt < 2; ++nt)
#pragma unroll
            for (int reg = 0; reg < 16; ++reg) {
                int row = (reg & 3) + 8 * (reg >> 2) + 4 * kg;
                int rr = w * 32 + row;
                int col = m0 + nt * 32 + n_l;
                if (rr < Mc) {
                    atomicAdd(&tmpML[((size_t)b * Mc + rr) * Lc + col], acc[nt][reg]);
                } else if (rr < 80) {
                    eat[(((size_t)b * Hc + h) * Ec + (rr - Mc)) * Lc + col] = acc[nt][reg];
                }
            }
    }
}

// ---------------- K3b: mention_att[b,m,m2] = sum_j tmpML[b,m,j]*mm[b,m2,j] ----------------
__global__ __launch_bounds__(256) void k_mention_att(const float* __restrict__ tmp,
                                                     const float* __restrict__ mm,
                                                     float* __restrict__ ma) {
    int idx = blockIdx.x * 256 + threadIdx.x;
    if (idx >= Bc * Mc * Mc) return;
    int b = idx / (Mc * Mc); int m = (idx / Mc) % Mc; int m2 = idx % Mc;
    float acc = 0.f;
    const float* t = tmp + (size_t)(b * Mc + m) * Lc;
    const float* r = mm + (size_t)(b * Mc + m2) * Lc;
    for (int j = 0; j < Lc; ++j) acc += t[j] * r[j];
    ma[idx] = acc;
}

// ---------------- K4: entity_att[b,e,m2] = sum_m em[b,e,m]*mention_att[b,m,m2] ----------------
__global__ __launch_bounds__(256) void k_entity_att(const float* __restrict__ em,
                                                    const float* __restrict__ ma,
                                                    float* __restrict__ ea) {
    int idx = blockIdx.x * 256 + threadIdx.x;
    if (idx >= Bc * Ec * Mc) return;
    int b = idx / (Ec * Mc); int e = (idx / Mc) % Ec; int m2 = idx % Mc;
    float acc = 0.f;
    const float* emr = em + (size_t)(b * Ec + e) * Mc;
    const float* mac = ma + (size_t)b * Mc * Mc + m2;
    for (int m = 0; m < Mc; ++m) acc += emr[m] * mac[(size_t)m * Mc];
    ea[idx] = acc;
}

// ---------------- K5: h_att/t_att normalize + h,t = att @ mention (f16 out) ----------------
__global__ __launch_bounds__(256) void k_ht(const int* __restrict__ hts,
                                            const float* __restrict__ em,
                                            const float* __restrict__ ea,
                                            const float* __restrict__ mention,
                                            f16* __restrict__ hB, f16* __restrict__ tB) {
    int bp = blockIdx.x; int b = bp / Pc;
    int hi = hts[bp * 2], ti = hts[bp * 2 + 1];
    float mask = (hi + ti != 0) ? 1.f : 0.f;
    __shared__ float hat[Mc], tat[Mc];
    __shared__ float sums[2];
    int tid = threadIdx.x;
    if (tid < Mc) {
        float hm = em[(size_t)(b * Ec + hi) * Mc + tid];
        float tm = em[(size_t)(b * Ec + ti) * Mc + tid];
        float eh = ea[(size_t)(b * Ec + hi) * Mc + tid];
        float et = ea[(size_t)(b * Ec + ti) * Mc + tid];
        hat[tid] = eh * tm * mask;
        tat[tid] = et * hm * mask;
    }
    __syncthreads();
    if (tid == 0) {
        float sh = 0.f, st = 0.f;
        for (int m = 0; m < Mc; ++m) { sh += hat[m]; st += tat[m]; }
        sums[0] = 1.f / (sh + MINV);
        sums[1] = 1.f / (st + MINV);
    }
    __syncthreads();
    float hnorm = sums[0], tnorm = sums[1];
    for (int d = tid; d < Dc; d += 256) {
        float ah = 0.f, at = 0.f;
        const float* mb = mention + (size_t)b * Mc * Dc + d;
        for (int m = 0; m < Mc; ++m) {
            float mv = mb[(size_t)m * Dc];
            ah += tat[m] * mv;
            at += hat[m] * mv;
        }
        hB[(size_t)bp * Dc + d] = (f16)(ah * tnorm * mask);
        tB[(size_t)bp * Dc + d] = (f16)(at * hnorm * mask);
    }
}

// ---------------- K6: em_tok[b,e,l] normalized ----------------
__global__ __launch_bounds__(256) void k_emtok(const float* __restrict__ em,
                                               const float* __restrict__ mm,
                                               float* __restrict__ emt) {
    int be = blockIdx.x; int b = be / Ec;
    __shared__ float row[Mc];
    __shared__ float red[256];
    __shared__ float inv;
    int tid = threadIdx.x;
    if (tid < Mc) row[tid] = em[(size_t)be * Mc + tid];
    __syncthreads();
    float v0 = 0.f, v1 = 0.f;
    {
        const float* mb0 = mm + (size_t)b * Mc * Lc + tid;
        const float* mb1 = mm + (size_t)b * Mc * Lc + tid + 256;
        for (int m = 0; m < Mc; ++m) {
            v0 += row[m] * mb0[(size_t)m * Lc];
            v1 += row[m] * mb1[(size_t)m * Lc];
        }
    }
    red[tid] = v0 + v1;
    __syncthreads();
    for (int s = 128; s > 0; s >>= 1) { if (tid < s) red[tid] += red[tid + s]; __syncthreads(); }
    if (tid == 0) inv = 1.f / (red[0] + MINV);
    __syncthreads();
    emt[(size_t)be * Lc + tid] = v0 * inv;
    emt[(size_t)be * Lc + tid + 256] = v1 * inv;
}

// ---------------- K8: ctx_att[b,p,l] = sum_h eat[b,h,hi,l]*eat[b,h,ti,l], normalized ----------------
__global__ __launch_bounds__(256) void k_ctxatt(const int* __restrict__ hts,
                                                const float* __restrict__ eat,
                                                float* __restrict__ ca) {
    int bp = blockIdx.x; int b = bp / Pc;
    int hi = hts[bp * 2], ti = hts[bp * 2 + 1];
    int tid = threadIdx.x;
    float a0 = 0.f, a1 = 0.f;
    for (int h = 0; h < Hc; ++h) {
        const float* ph = eat + ((size_t)(b * Hc + h) * Ec + hi) * Lc;
        const float* pt = eat + ((size_t)(b * Hc + h) * Ec + ti) * Lc;
        a0 += ph[tid] * pt[tid];
        a1 += ph[tid + 256] * pt[tid + 256];
    }
    __shared__ float red[256];
    __shared__ float inv;
    red[tid] = a0 + a1;
    __syncthreads();
    for (int s = 128; s > 0; s >>= 1) { if (tid < s) red[tid] += red[tid + s]; __syncthreads(); }
    if (tid == 0) inv = 1.f / (red[0] + MINV);
    __syncthreads();
    ca[(size_t)bp * Lc + tid] = a0 * inv;
    ca[(size_t)bp * Lc + tid + 256] = a1 * inv;
}

// ---------------- K9: context_info via MFMA (f16) ----------------
__global__ __launch_bounds__(256) void k_ctxinfo_mfma(const int* __restrict__ hts,
                                                      const float* __restrict__ ca,
                                                      const f16* __restrict__ ctxT,
                                                      f16* __restrict__ ci) {
    __shared__ __align__(16) f16 As[2][64 * 64];
    __shared__ __align__(16) f16 Bs[2][64 * 64];
    __shared__ float maskS[64];
    int id = blockIdx.x;            // ((b*8+pt)*12+dt)
    int dt = id % 12; int pt = (id / 12) % 8; int b = id / 96;
    int p0 = pt * 64, d0 = dt * 64;
    int tid = threadIdx.x;
    int w = tid >> 6, lane = tid & 63;
    int w_m = w & 1, w_n = w >> 1;
    int m_l = lane & 31, kg = lane >> 5;
    int r0 = tid >> 3, cc0 = tid & 7;
    int r1 = r0 + 32;
    if (tid < 64) {
        int bp = b * Pc + p0 + tid;
        maskS[tid] = (hts[bp * 2] + hts[bp * 2 + 1] != 0) ? 1.f : 0.f;
    }
    f16x8 ar0, ar1, br0, br1;
    auto loadt = [&](int it) {
        int k0 = it * 64;
        const float* A0 = ca + (size_t)(b * Pc + p0 + r0) * Lc + k0 + cc0 * 8;
        const float* A1 = ca + (size_t)(b * Pc + p0 + r1) * Lc + k0 + cc0 * 8;
#pragma unroll
        for (int j = 0; j < 8; ++j) { ar0[j] = (f16)A0[j]; ar1[j] = (f16)A1[j]; }
        br0 = *(const f16x8*)(ctxT + (size_t)(b * Dc + d0 + r0) * Lc + k0 + cc0 * 8);
        br1 = *(const f16x8*)(ctxT + (size_t)(b * Dc + d0 + r1) * Lc + k0 + cc0 * 8);
    };
    auto writet = [&](int p) {
        ((f16x8*)As[p])[r0 * 8 + (cc0 ^ (r0 & 7))] = ar0;
        ((f16x8*)As[p])[r1 * 8 + (cc0 ^ (r1 & 7))] = ar1;
        ((f16x8*)Bs[p])[r0 * 8 + (cc0 ^ (r0 & 7))] = br0;
        ((f16x8*)Bs[p])[r1 * 8 + (cc0 ^ (r1 & 7))] = br1;
    };
    loadt(0); writet(0); loadt(1);
    f32x16 acc;
#pragma unroll
    for (int i = 0; i < 16; ++i) acc[i] = 0.f;
    int ar = w_m * 32 + m_l;
    int br = w_n * 32 + m_l;
    for (int it = 0; it < 8; ++it) {
        int p = it & 1;
        __syncthreads();
        if (it < 7) writet(p ^ 1);
        if (it < 6) loadt(it + 2);
#pragma unroll
        for (int s = 0; s < 4; ++s) {
            int ck = s * 2 + kg;
            f16x8 a = ((const f16x8*)As[p])[ar * 8 + (ck ^ (ar & 7))];
            f16x8 bv = ((const f16x8*)Bs[p])[br * 8 + (ck ^ (br & 7))];
            acc = __builtin_amdgcn_mfma_f32_32x32x16_f16(a, bv, acc, 0, 0, 0);
        }
    }
#pragma unroll
    for (int reg = 0; reg < 16; ++reg) {
        int row = (reg & 3) + 8 * (reg >> 2) + 4 * kg;
        int p = p0 + w_m * 32 + row;
        int d = d0 + w_n * 32 + m_l;
        ci[(size_t)(b * Pc + p) * Dc + d] = (f16)(acc[reg] * maskS[w_m * 32 + row]);
    }
}

// ---------------- K10: MFMA proj merged (z=2), f16 ----------------
__global__ __launch_bounds__(256) void k_proj_mfma(const f16* __restrict__ Xh, const f16* __restrict__ Wh,
                                                   const float* __restrict__ bh,
                                                   const f16* __restrict__ Xt, const f16* __restrict__ Wt,
                                                   const float* __restrict__ bt,
                                                   const f16* __restrict__ Xc, const f16* __restrict__ Whc,
                                                   const float* __restrict__ bhc,
                                                   const f16* __restrict__ Wtc, const float* __restrict__ btc,
                                                   f16* __restrict__ outh, f16* __restrict__ outt) {
    __shared__ __align__(16) f16 Xs[2][64 * 64];
    __shared__ __align__(16) f16 Ws[2][64 * 64];
    int z = blockIdx.z;
    const f16* X1 = z ? Xt : Xh;
    const f16* W1 = z ? Wt : Wh;
    const float* b1 = z ? bt : bh;
    const f16* W2 = z ? Wtc : Whc;
    const float* b2 = z ? btc : bhc;
    f16* outp = z ? outt : outh;
    int m0 = blockIdx.x * 64, n0 = blockIdx.y * 64;
    int tid = threadIdx.x;
    int w = tid >> 6, lane = tid & 63;
    int w_m = w & 1, w_n = w >> 1;
    int m_l = lane & 31, kg = lane >> 5;
    const f16* Xarr[2] = {X1, Xc};
    const f16* Warr[2] = {W1, W2};
    int r0 = tid >> 3, cc0 = tid & 7;
    int r1 = r0 + 32;
    f16x8 xr0, xr1, wr0, wr1;
    auto loadt = [&](int it) {
        int src = it / 12; int k0 = (it % 12) * 64;
        const f16* X = Xarr[src]; const f16* W = Warr[src];
        xr0 = *(const f16x8*)(X + (size_t)(m0 + r0) * Dc + k0 + cc0 * 8);
        xr1 = *(const f16x8*)(X + (size_t)(m0 + r1) * Dc + k0 + cc0 * 8);
        wr0 = *(const f16x8*)(W + (size_t)(n0 + r0) * Dc + k0 + cc0 * 8);
        wr1 = *(const f16x8*)(W + (size_t)(n0 + r1) * Dc + k0 + cc0 * 8);
    };
    auto writet = [&](int p) {
        ((f16x8*)Xs[p])[r0 * 8 + (cc0 ^ (r0 & 7))] = xr0;
        ((f16x8*)Xs[p])[r1 * 8 + (cc0 ^ (r1 & 7))] = xr1;
        ((f16x8*)Ws[p])[r0 * 8 + (cc0 ^ (r0 & 7))] = wr0;
        ((f16x8*)Ws[p])[r1 * 8 + (cc0 ^ (r1 & 7))] = wr1;
    };
    loadt(0); writet(0); loadt(1);
    f32x16 acc;
#pragma unroll
    for (int i = 0; i < 16; ++i) acc[i] = 0.f;
    int ar = w_m * 32 + m_l;
    int br = w_n * 32 + m_l;
    for (int it = 0; it < 24; ++it) {
        int p = it & 1;
        __syncthreads();
        if (it < 23) writet(p ^ 1);
        if (it < 22) loadt(it + 2);
#pragma unroll
        for (int s = 0; s < 4; ++s) {
            int ck = s * 2 + kg;
            f16x8 a = ((const f16x8*)Xs[p])[ar * 8 + (ck ^ (ar & 7))];
            f16x8 b = ((const f16x8*)Ws[p])[br * 8 + (ck ^ (br & 7))];
            acc = __builtin_amdgcn_mfma_f32_32x32x16_f16(a, b, acc, 0, 0, 0);
        }
    }
#pragma unroll
    for (int reg = 0; reg < 16; ++reg) {
        int row = (reg & 3) + 8 * (reg >> 2) + 4 * kg;
        int m = m0 + w_m * 32 + row;
        int n = n0 + w_n * 32 + m_l;
        float v = tanhf(acc[reg] + b1[n] + b2[n]);
        outp[(size_t)m * Dc + n] = (f16)v;
    }
}

// ---------------- K11a: init out with bias ----------------
__global__ __launch_bounds__(256) void k_outinit(const float* __restrict__ cb, float* __restrict__ out) {
    int idx = blockIdx.x * 256 + threadIdx.x;
    if (idx < Bc * Pc * Rc) out[idx] = cb[idx % Rc];
}

// ---------------- K11b prep: swizzle clasW into MFMA-fragment layout (f16) ----------------
__global__ __launch_bounds__(256) void k_wprep(const float* __restrict__ W, f16* __restrict__ Wp) {
    int gid = blockIdx.x * 256 + threadIdx.x;
    if (gid >= 768 * 16 * 64) return;
    int lane = gid & 63; int f = gid >> 6;
    int rt = f & 3; int s = (f >> 2) & 3; int c = f >> 4;
    int n_l = lane & 31, kg = lane >> 5;
    int r = rt * 32 + n_l;
    f16x8 v;
    if (r < Rc) {
        const float* src = W + (size_t)r * (Dc * 64) + c * 64 + s * 16 + kg * 8;
#pragma unroll
        for (int j = 0; j < 8; ++j) v[j] = (f16)src[j];
    } else {
#pragma unroll
        for (int j = 0; j < 8; ++j) v[j] = (f16)0.f;
    }
    ((f16x8*)Wp)[gid] = v;
}

// ---------------- K11b v4: group bilinear f16, direct B loads, 3 waves/SIMD ----------------
__global__ __launch_bounds__(256, 3) void k_bilin4(const f16* __restrict__ hF, const f16* __restrict__ tF,
                                                   const f16* __restrict__ Wp, float* __restrict__ outp) {
    __shared__ __align__(16) char smemraw[16384 + 6400];
    f16* tS = (f16*)smemraw;                 // [128][8 chunks ^(bp&7)][8] = 16 KB
    f16* hS = (f16*)(smemraw + 16384);       // [128][25] = 6.4 KB
    float* mbuf = (float*)smemraw;           // epilogue alias: [128][32] = 16 KB
    int id = blockIdx.x;
    int tile = id >> 5;
    int slice = id & 31;
    int bp0 = tile * 128;
    int tid = threadIdx.x;
    int w = tid >> 6, lane = tid & 63;
    int w_m = w & 1, w_i = w >> 1;
    int m_l = lane & 31, kg = lane >> 5;
    int c0 = slice * 24, cEnd = c0 + 24;

    for (int idx = tid; idx < 128 * 24; idx += 256) {
        int bp = idx / 24, i = idx % 24;
        hS[bp * 25 + i] = hF[(size_t)(bp0 + bp) * Dc + c0 + i];
    }

    f32x16 acc[2][4];
#pragma unroll
    for (int mt = 0; mt < 2; ++mt)
#pragma unroll
        for (int rt = 0; rt < 4; ++rt)
#pragma unroll
            for (int i = 0; i < 16; ++i) acc[mt][rt][i] = 0.f;

    int rowA = w_m * 64 + m_l;
    int rowB = rowA + 32;

    const f16x8* WpB = (const f16x8*)Wp;
    int c = c0;
    while (c < cEnd) {
        int n = c >> 6;
        int segEnd = (cEnd < (n + 1) * 64) ? cEnd : (n + 1) * 64;
        __syncthreads();
        for (int idx = tid; idx < 128 * 8; idx += 256) {
            int bp = idx >> 3, cc = idx & 7;
            f16x8 tv = *(const f16x8*)(tF + (size_t)(bp0 + bp) * Dc + n * 64 + cc * 8);
            ((f16x8*)tS)[bp * 8 + (cc ^ (bp & 7))] = tv;
        }
        __syncthreads();
        for (int cc = c + w_i; cc < segEnd; cc += 2) {
            int ii = cc - c0;
            f16 hv0 = hS[rowA * 25 + ii];
            f16 hv1 = hS[rowB * 25 + ii];
            const f16x8* wpb = WpB + (size_t)cc * 16 * 64 + lane;
#pragma unroll
            for (int s = 0; s < 4; ++s) {
                int ck = s * 2 + kg;
                f16x8 tv0 = ((const f16x8*)tS)[rowA * 8 + (ck ^ (rowA & 7))];
                f16x8 tv1 = ((const f16x8*)tS)[rowB * 8 + (ck ^ (rowB & 7))];
                f16x8 a0 = tv0 * hv0;
                f16x8 a1 = tv1 * hv1;
                f16x8 B0 = wpb[(s * 4 + 0) * 64];
                f16x8 B1 = wpb[(s * 4 + 1) * 64];
                f16x8 B2 = wpb[(s * 4 + 2) * 64];
                f16x8 B3 = wpb[(s * 4 + 3) * 64];
                acc[0][0] = __builtin_amdgcn_mfma_f32_32x32x16_f16(a0, B0, acc[0][0], 0, 0, 0);
                acc[1][0] = __builtin_amdgcn_mfma_f32_32x32x16_f16(a1, B0, acc[1][0], 0, 0, 0);
                acc[0][1] = __builtin_amdgcn_mfma_f32_32x32x16_f16(a0, B1, acc[0][1], 0, 0, 0);
                acc[1][1] = __builtin_amdgcn_mfma_f32_32x32x16_f16(a1, B1, acc[1][1], 0, 0, 0);
                acc[0][2] = __builtin_amdgcn_mfma_f32_32x32x16_f16(a0, B2, acc[0][2], 0, 0, 0);
                acc[1][2] = __builtin_amdgcn_mfma_f32_32x32x16_f16(a1, B2, acc[1][2], 0, 0, 0);
                acc[0][3] = __builtin_amdgcn_mfma_f32_32x32x16_f16(a0, B3, acc[0][3], 0, 0, 0);
                acc[1][3] = __builtin_amdgcn_mfma_f32_32x32x16_f16(a1, B3, acc[1][3], 0, 0, 0);
            }
        }
        c = segEnd;
    }

    // epilogue: 4 rounds (one rt each), merge w_i pairs via mbuf then atomicAdd
    for (int rt = 0; rt < 4; ++rt) {
        __syncthreads();
        if (w_i == 1) {
#pragma unroll
            for (int mt = 0; mt < 2; ++mt)
#pragma unroll
                for (int reg = 0; reg < 16; ++reg) {
                    int row = (reg & 3) + 8 * (reg >> 2) + 4 * kg;
                    mbuf[(w_m * 64 + mt * 32 + row) * 32 + m_l] = acc[mt][rt][reg];
                }
        }
        __syncthreads();
        if (w_i == 0) {
            int r = rt * 32 + m_l;
            if (r < Rc) {
#pragma unroll
                for (int mt = 0; mt < 2; ++mt)
#pragma unroll
                    for (int reg = 0; reg < 16; ++reg) {
                        int row = (reg & 3) + 8 * (reg >> 2) + 4 * kg;
                        int bp = bp0 + w_m * 64 + mt * 32 + row;
                        float v = acc[mt][rt][reg] + mbuf[(w_m * 64 + mt * 32 + row) * 32 + m_l];
                        atomicAdd(&outp[(size_t)bp * Rc + r], v);
                    }
            }
        }
    }
}

extern "C" void kernel_launch(void* const* d_in, const int* in_sizes, int n_in,
                              void* d_out, int out_size, void* d_ws, size_t ws_size,
                              hipStream_t stream) {
    const float* context   = (const float*)d_in[0];
    const float* attention = (const float*)d_in[1];
    const float* mm        = (const float*)d_in[2];
    const float* em        = (const float*)d_in[3];
    const int*   hts       = (const int*)d_in[4];
    const float* hW        = (const float*)d_in[5];
    const float* hb        = (const float*)d_in[6];
    const float* tW        = (const float*)d_in[7];
    const float* tb        = (const float*)d_in[8];
    const float* hcW       = (const float*)d_in[9];
    const float* hcb       = (const float*)d_in[10];
    const float* tcW       = (const float*)d_in[11];
    const float* tcb       = (const float*)d_in[12];
    const float* clasW     = (const float*)d_in[13];
    const float* clasb     = (const float*)d_in[14];
    float* out = (float*)d_out;

    char* wsb = (char*)d_ws;
    auto alloc = [&](size_t bytes) { char* p = wsb; wsb += (bytes + 255) & ~(size_t)255; return p; };
    float* mention     = (float*)alloc((size_t)Bc * Mc * Dc * 4);
    float* tmpML       = (float*)alloc((size_t)Bc * Mc * Lc * 4);
    float* mention_att = (float*)alloc((size_t)Bc * Mc * Mc * 4);
    float* entity_att  = (float*)alloc((size_t)Bc * Ec * Mc * 4);
    float* em_tok      = (float*)alloc((size_t)Bc * Ec * Lc * 4);
    float* ent_att     = (float*)alloc((size_t)Bc * Hc * Ec * Lc * 4);
    float* ctx_att     = (float*)alloc((size_t)Bc * Pc * Lc * 4);
    f16* h_buf   = (f16*)alloc((size_t)Bc * Pc * Dc * 2);
    f16* t_buf   = (f16*)alloc((size_t)Bc * Pc * Dc * 2);
    f16* ctxinfo = (f16*)alloc((size_t)Bc * Pc * Dc * 2);
    f16* h_fin   = (f16*)alloc((size_t)Bc * Pc * Dc * 2);
    f16* t_fin   = (f16*)alloc((size_t)Bc * Pc * Dc * 2);
    f16* hWb     = (f16*)alloc((size_t)Dc * Dc * 2);
    f16* tWb     = (f16*)alloc((size_t)Dc * Dc * 2);
    f16* hcWb    = (f16*)alloc((size_t)Dc * Dc * 2);
    f16* tcWb    = (f16*)alloc((size_t)Dc * Dc * 2);
    f16* ctxT    = (f16*)alloc((size_t)Bc * Dc * Lc * 2);
    f16* Wp      = (f16*)alloc((size_t)768 * 16 * 64 * 8 * 2);

    hipMemsetAsync(tmpML, 0, (size_t)Bc * Mc * Lc * 4, stream);
    k_cvt4<<<dim3(2048), dim3(256), 0, stream>>>(hW, tW, hcW, tcW, hWb, tWb, hcWb, tcWb);
    k_wprep<<<dim3(3072), dim3(256), 0, stream>>>(clasW, Wp);
    k_tran<<<dim3(384), dim3(256), 0, stream>>>(context, ctxT);

    k_emtok<<<dim3(Bc * Ec), dim3(256), 0, stream>>>(em, mm, em_tok);
    k_attpass<<<dim3(Bc * Hc * 8), dim3(256), 0, stream>>>(mm, em_tok, attention, tmpML, ent_att);
    k_mention_mfma<<<dim3(Bc * 12), dim3(256), 0, stream>>>(mm, ctxT, mention);
    k_mention_att<<<dim3((Bc * Mc * Mc + 255) / 256), dim3(256), 0, stream>>>(tmpML, mm, mention_att);
    k_entity_att<<<dim3((Bc * Ec * Mc + 255) / 256), dim3(256), 0, stream>>>(em, mention_att, entity_att);
    k_ht<<<dim3(Bc * Pc), dim3(256), 0, stream>>>(hts, em, entity_att, mention, h_buf, t_buf);
    k_ctxatt<<<dim3(Bc * Pc), dim3(256), 0, stream>>>(hts, ent_att, ctx_att);
    k_ctxinfo_mfma<<<dim3(384), dim3(256), 0, stream>>>(hts, ctx_att, ctxT, ctxinfo);
    k_proj_mfma<<<dim3(32, 12, 2), dim3(256), 0, stream>>>(h_buf, hWb, hb, t_buf, tWb, tb,
                                                           ctxinfo, hcWb, hcb, tcWb, tcb, h_fin, t_fin);
    k_outinit<<<dim3((Bc * Pc * Rc + 255) / 256), dim3(256), 0, stream>>>(clasb, out);
    k_bilin4<<<dim3(512), dim3(256), 0, stream>>>(h_fin, t_fin, Wp, out);
}

// Round 6
// 391.179 us; speedup vs baseline: 1.1070x; 1.1070x over previous
//
#include <hip/hip_runtime.h>
#include <math.h>

#define Bc 4
#define Lc 512
#define Dc 768
#define Hc 12
#define Mc 48
#define Ec 32
#define Pc 512
#define Rc 97
#define MINV 1e-30f

typedef _Float16 f16;
typedef __attribute__((ext_vector_type(8))) _Float16 f16x8;
typedef __attribute__((ext_vector_type(16))) float f32x16;

// ---------------- K_prep: fused cvt4 (weights->f16) + wprep (clasW swizzle) + tran (ctx transpose) ----------------
__global__ __launch_bounds__(256) void k_prep(const float* __restrict__ hW, const float* __restrict__ tW,
                                              const float* __restrict__ hcW, const float* __restrict__ tcW,
                                              f16* __restrict__ hWb, f16* __restrict__ tWb,
                                              f16* __restrict__ hcWb, f16* __restrict__ tcWb,
                                              const float* __restrict__ clasW, f16* __restrict__ Wp,
                                              const float* __restrict__ ctx, f16* __restrict__ ctxT) {
    __shared__ f16 Ts[64][72];
    int bid = blockIdx.x;
    int tid = threadIdx.x;
    if (bid < 2048) {
        // region A: 4x DxD weight converts, grid-stride
        const int DD = Dc * Dc;
        int i = bid * 256 + tid;
        int stride = 2048 * 256;
        for (; i < 4 * DD; i += stride) {
            int sel = i / DD, j = i % DD;
            const float* s = (sel == 0) ? hW : (sel == 1) ? tW : (sel == 2) ? hcW : tcW;
            f16* d = (sel == 0) ? hWb : (sel == 1) ? tWb : (sel == 2) ? hcWb : tcWb;
            d[j] = (f16)s[j];
        }
    } else if (bid < 5120) {
        // region B: clasW -> MFMA-fragment layout. frag f=(c*4+s)*4+rt, elem lane*8+j
        int gid = (bid - 2048) * 256 + tid;   // < 768*16*64
        int lane = gid & 63; int f = gid >> 6;
        int rt = f & 3; int s = (f >> 2) & 3; int c = f >> 4;
        int n_l = lane & 31, kg = lane >> 5;
        int r = rt * 32 + n_l;
        f16x8 v;
        if (r < Rc) {
            const float* src = clasW + (size_t)r * (Dc * 64) + c * 64 + s * 16 + kg * 8;
#pragma unroll
            for (int j = 0; j < 8; ++j) v[j] = (f16)src[j];
        } else {
#pragma unroll
            for (int j = 0; j < 8; ++j) v[j] = (f16)0.f;
        }
        ((f16x8*)Wp)[gid] = v;
    } else {
        // region C: context transpose -> ctxT[b][d][l] f16
        int id = bid - 5120;           // ((b*8+lt)*12+dt)
        int dt = id % 12; int lt = (id / 12) % 8; int b = id / 96;
        int l0 = lt * 64, d0 = dt * 64;
        int r = tid >> 2, cg = tid & 3;
        const float* src = ctx + ((size_t)b * Lc + l0 + r) * Dc + d0 + cg * 16;
#pragma unroll
        for (int u = 0; u < 4; ++u) {
            float4 v = ((const float4*)src)[u];
            Ts[cg * 16 + u * 4 + 0][r] = (f16)v.x;
            Ts[cg * 16 + u * 4 + 1][r] = (f16)v.y;
            Ts[cg * 16 + u * 4 + 2][r] = (f16)v.z;
            Ts[cg * 16 + u * 4 + 3][r] = (f16)v.w;
        }
        __syncthreads();
        int dr = tid >> 2, seg = tid & 3;
        f16* dst = ctxT + ((size_t)b * Dc + d0 + dr) * Lc + l0 + seg * 16;
        f16x8 o0, o1;
#pragma unroll
        for (int j = 0; j < 8; ++j) { o0[j] = Ts[dr][seg * 16 + j]; o1[j] = Ts[dr][seg * 16 + 8 + j]; }
        *(f16x8*)dst = o0;
        *(f16x8*)(dst + 8) = o1;
    }
}

// ---------------- K1: mention = mm @ ctx via MFMA (M=48 pad 64, N=64 tiles, K=512) ----------------
__global__ __launch_bounds__(256) void k_mention_mfma(const float* __restrict__ mm,
                                                      const f16* __restrict__ ctxT,
                                                      float* __restrict__ mention) {
    __shared__ __align__(16) f16 As[2][64 * 64];
    __shared__ __align__(16) f16 Bs[2][64 * 64];
    int id = blockIdx.x;            // b*12+dt
    int dt = id % 12; int b = id / 12;
    int d0 = dt * 64;
    int tid = threadIdx.x;
    int w = tid >> 6, lane = tid & 63;
    int w_m = w & 1, w_n = w >> 1;
    int m_l = lane & 31, kg = lane >> 5;
    int r0 = tid >> 3, cc0 = tid & 7;
    int r1 = r0 + 32;
    int mr0 = (r0 < Mc) ? r0 : r0 - Mc;
    int mr1 = (r1 < Mc) ? r1 : r1 - Mc;
    f16x8 ar0, ar1, br0, br1;
    auto loadt = [&](int it) {
        int k0 = it * 64;
        const float* A0 = mm + ((size_t)b * Mc + mr0) * Lc + k0 + cc0 * 8;
        const float* A1 = mm + ((size_t)b * Mc + mr1) * Lc + k0 + cc0 * 8;
#pragma unroll
        for (int j = 0; j < 8; ++j) { ar0[j] = (f16)A0[j]; ar1[j] = (f16)A1[j]; }
        br0 = *(const f16x8*)(ctxT + ((size_t)b * Dc + d0 + r0) * Lc + k0 + cc0 * 8);
        br1 = *(const f16x8*)(ctxT + ((size_t)b * Dc + d0 + r1) * Lc + k0 + cc0 * 8);
    };
    auto writet = [&](int p) {
        ((f16x8*)As[p])[r0 * 8 + (cc0 ^ (r0 & 7))] = ar0;
        ((f16x8*)As[p])[r1 * 8 + (cc0 ^ (r1 & 7))] = ar1;
        ((f16x8*)Bs[p])[r0 * 8 + (cc0 ^ (r0 & 7))] = br0;
        ((f16x8*)Bs[p])[r1 * 8 + (cc0 ^ (r1 & 7))] = br1;
    };
    loadt(0); writet(0); loadt(1);
    f32x16 acc;
#pragma unroll
    for (int i = 0; i < 16; ++i) acc[i] = 0.f;
    int ar = w_m * 32 + m_l;
    int br = w_n * 32 + m_l;
    for (int it = 0; it < 8; ++it) {
        int p = it & 1;
        __syncthreads();
        if (it < 7) writet(p ^ 1);
        if (it < 6) loadt(it + 2);
#pragma unroll
        for (int s = 0; s < 4; ++s) {
            int ck = s * 2 + kg;
            f16x8 a = ((const f16x8*)As[p])[ar * 8 + (ck ^ (ar & 7))];
            f16x8 bv = ((const f16x8*)Bs[p])[br * 8 + (ck ^ (br & 7))];
            acc = __builtin_amdgcn_mfma_f32_32x32x16_f16(a, bv, acc, 0, 0, 0);
        }
    }
#pragma unroll
    for (int reg = 0; reg < 16; ++reg) {
        int row = (reg & 3) + 8 * (reg >> 2) + 4 * kg;
        int m = w_m * 32 + row;
        if (m < Mc) mention[((size_t)b * Mc + m) * Dc + d0 + w_n * 32 + m_l] = acc[reg];
    }
}

// ---------------- K2 fused: one pass over attention ----------------
__global__ __launch_bounds__(256) void k_attpass(const float* __restrict__ mm,
                                                 const float* __restrict__ emt,
                                                 const float* __restrict__ att,
                                                 float* __restrict__ tmpML,
                                                 float* __restrict__ eat) {
    __shared__ __align__(16) f16 Ss[96 * 64];
    __shared__ __align__(16) f16 attS[64 * 64];
    int id = blockIdx.x;
    int mt = id & 7; int bh = id >> 3;
    int b = bh / Hc, h = bh % Hc;
    int m0 = mt * 64;
    int tid = threadIdx.x;
    int w = tid >> 6, lane = tid & 63;
    int n_l = lane & 31, kg = lane >> 5;

    const float* ab = att + (size_t)bh * Lc * Lc + m0;
    int mRow = tid & 63, lg = tid >> 6;
    float pre[16];
#pragma unroll
    for (int q = 0; q < 16; ++q) pre[q] = ab[(size_t)(lg * 16 + q) * Lc + mRow];

    f32x16 acc[2];
#pragma unroll
    for (int nt = 0; nt < 2; ++nt)
#pragma unroll
        for (int i = 0; i < 16; ++i) acc[nt][i] = 0.f;

    for (int kc = 0; kc < 8; ++kc) {
        __syncthreads();
#pragma unroll
        for (int half = 0; half < 2; ++half) {
            int cc = lg * 2 + half;
            f16x8 v;
#pragma unroll
            for (int jj = 0; jj < 8; ++jj) v[jj] = (f16)pre[half * 8 + jj];
            ((f16x8*)attS)[mRow * 8 + (cc ^ (mRow & 7))] = v;
        }
#pragma unroll
        for (int k = 0; k < 3; ++k) {
            int idx = tid + k * 256;
            int row = idx >> 3, cc = idx & 7;
            f16x8 v;
            if (row < Mc) {
                const float* src = mm + ((size_t)b * Mc + row) * Lc + kc * 64 + cc * 8;
#pragma unroll
                for (int j = 0; j < 8; ++j) v[j] = (f16)src[j];
            } else if (row < 80) {
                const float* src = emt + ((size_t)b * Ec + row - Mc) * Lc + kc * 64 + cc * 8;
#pragma unroll
                for (int j = 0; j < 8; ++j) v[j] = (f16)src[j];
            } else {
#pragma unroll
                for (int j = 0; j < 8; ++j) v[j] = (f16)0.f;
            }
            ((f16x8*)Ss)[row * 8 + (cc ^ (row & 7))] = v;
        }
        if (kc < 7) {
#pragma unroll
            for (int q = 0; q < 16; ++q)
                pre[q] = ab[(size_t)((kc + 1) * 64 + lg * 16 + q) * Lc + mRow];
        }
        __syncthreads();
        if (w < 3) {
            int arow = w * 32 + n_l;
#pragma unroll
            for (int kk = 0; kk < 4; ++kk) {
                int cc = kk * 2 + kg;
                f16x8 a = ((const f16x8*)Ss)[arow * 8 + (cc ^ (arow & 7))];
#pragma unroll
                for (int nt = 0; nt < 2; ++nt) {
                    int bcol = nt * 32 + n_l;
                    f16x8 bb = ((const f16x8*)attS)[bcol * 8 + (cc ^ (bcol & 7))];
                    acc[nt] = __builtin_amdgcn_mfma_f32_32x32x16_f16(a, bb, acc[nt], 0, 0, 0);
                }
            }
        }
    }
    if (w < 3) {
#pragma unroll
        for (int nt = 0; nt < 2; ++nt)
#pragma unroll
            for (int reg = 0; reg < 16; ++reg) {
                int row = (reg & 3) + 8 * (reg >> 2) + 4 * kg;
                int rr = w * 32 + row;
                int col = m0 + nt * 32 + n_l;
                if (rr < Mc) {
                    atomicAdd(&tmpML[((size_t)b * Mc + rr) * Lc + col], acc[nt][reg]);
                } else if (rr < 80) {
                    eat[(((size_t)b * Hc + h) * Ec + (rr - Mc)) * Lc + col] = acc[nt][reg];
                }
            }
    }
}

// ---------------- K3 fused: mention_att (LDS only) + entity_att. grid = b*4 (m2 column quarters) ----------------
__global__ __launch_bounds__(256) void k_ment_ent(const float* __restrict__ tmp,
                                                  const float* __restrict__ mm,
                                                  const float* __restrict__ em,
                                                  float* __restrict__ ea) {
    __shared__ float maS[Mc][12];
    int b = blockIdx.x >> 2, q = blockIdx.x & 3;
    int tid = threadIdx.x;
    for (int idx = tid; idx < Mc * 12; idx += 256) {
        int m = idx / 12, m2 = q * 12 + idx % 12;
        float acc = 0.f;
        const float* t = tmp + (size_t)(b * Mc + m) * Lc;
        const float* r = mm + (size_t)(b * Mc + m2) * Lc;
        for (int j = 0; j < Lc; ++j) acc += t[j] * r[j];
        maS[m][idx % 12] = acc;
    }
    __syncthreads();
    for (int idx = tid; idx < Ec * 12; idx += 256) {
        int e = idx / 12, m2q = idx % 12;
        float acc = 0.f;
        const float* emr = em + (size_t)(b * Ec + e) * Mc;
        for (int m = 0; m < Mc; ++m) acc += emr[m] * maS[m][m2q];
        ea[((size_t)b * Ec + e) * Mc + q * 12 + m2q] = acc;
    }
}

// ---------------- K5 fused: ctx_att + h/t build, per bp ----------------
__global__ __launch_bounds__(256) void k_htctx(const int* __restrict__ hts,
                                               const float* __restrict__ em,
                                               const float* __restrict__ ea,
                                               const float* __restrict__ mention,
                                               const float* __restrict__ eat,
                                               f16* __restrict__ hB, f16* __restrict__ tB,
                                               float* __restrict__ ca) {
    int bp = blockIdx.x; int b = bp / Pc;
    int hi = hts[bp * 2], ti = hts[bp * 2 + 1];
    float mask = (hi + ti != 0) ? 1.f : 0.f;
    int tid = threadIdx.x;
    __shared__ float red[256];
    __shared__ float inv;
    __shared__ float hat[Mc], tat[Mc];
    __shared__ float sums[2];

    // --- part 1: ctx_att ---
    float a0 = 0.f, a1 = 0.f;
    for (int h = 0; h < Hc; ++h) {
        const float* ph = eat + ((size_t)(b * Hc + h) * Ec + hi) * Lc;
        const float* pt = eat + ((size_t)(b * Hc + h) * Ec + ti) * Lc;
        a0 += ph[tid] * pt[tid];
        a1 += ph[tid + 256] * pt[tid + 256];
    }
    red[tid] = a0 + a1;
    __syncthreads();
    for (int s = 128; s > 0; s >>= 1) { if (tid < s) red[tid] += red[tid + s]; __syncthreads(); }
    if (tid == 0) inv = 1.f / (red[0] + MINV);
    // --- part 2: h_att/t_att ---
    if (tid < Mc) {
        float hm = em[(size_t)(b * Ec + hi) * Mc + tid];
        float tm = em[(size_t)(b * Ec + ti) * Mc + tid];
        float eh = ea[(size_t)(b * Ec + hi) * Mc + tid];
        float et = ea[(size_t)(b * Ec + ti) * Mc + tid];
        hat[tid] = eh * tm * mask;
        tat[tid] = et * hm * mask;
    }
    __syncthreads();
    ca[(size_t)bp * Lc + tid] = a0 * inv;
    ca[(size_t)bp * Lc + tid + 256] = a1 * inv;
    if (tid == 0) {
        float sh = 0.f, st = 0.f;
        for (int m = 0; m < Mc; ++m) { sh += hat[m]; st += tat[m]; }
        sums[0] = 1.f / (sh + MINV);
        sums[1] = 1.f / (st + MINV);
    }
    __syncthreads();
    float hnorm = sums[0], tnorm = sums[1];
    for (int d = tid; d < Dc; d += 256) {
        float ah = 0.f, at = 0.f;
        const float* mb = mention + (size_t)b * Mc * Dc + d;
        for (int m = 0; m < Mc; ++m) {
            float mv = mb[(size_t)m * Dc];
            ah += tat[m] * mv;
            at += hat[m] * mv;
        }
        hB[(size_t)bp * Dc + d] = (f16)(ah * tnorm * mask);
        tB[(size_t)bp * Dc + d] = (f16)(at * hnorm * mask);
    }
}

// ---------------- K6: em_tok[b,e,l] normalized ----------------
__global__ __launch_bounds__(256) void k_emtok(const float* __restrict__ em,
                                               const float* __restrict__ mm,
                                               float* __restrict__ emt) {
    int be = blockIdx.x; int b = be / Ec;
    __shared__ float row[Mc];
    __shared__ float red[256];
    __shared__ float inv;
    int tid = threadIdx.x;
    if (tid < Mc) row[tid] = em[(size_t)be * Mc + tid];
    __syncthreads();
    float v0 = 0.f, v1 = 0.f;
    {
        const float* mb0 = mm + (size_t)b * Mc * Lc + tid;
        const float* mb1 = mm + (size_t)b * Mc * Lc + tid + 256;
        for (int m = 0; m < Mc; ++m) {
            v0 += row[m] * mb0[(size_t)m * Lc];
            v1 += row[m] * mb1[(size_t)m * Lc];
        }
    }
    red[tid] = v0 + v1;
    __syncthreads();
    for (int s = 128; s > 0; s >>= 1) { if (tid < s) red[tid] += red[tid + s]; __syncthreads(); }
    if (tid == 0) inv = 1.f / (red[0] + MINV);
    __syncthreads();
    emt[(size_t)be * Lc + tid] = v0 * inv;
    emt[(size_t)be * Lc + tid + 256] = v1 * inv;
}

// ---------------- K9: context_info via MFMA (f16) ----------------
__global__ __launch_bounds__(256) void k_ctxinfo_mfma(const int* __restrict__ hts,
                                                      const float* __restrict__ ca,
                                                      const f16* __restrict__ ctxT,
                                                      f16* __restrict__ ci) {
    __shared__ __align__(16) f16 As[2][64 * 64];
    __shared__ __align__(16) f16 Bs[2][64 * 64];
    __shared__ float maskS[64];
    int id = blockIdx.x;            // ((b*8+pt)*12+dt)
    int dt = id % 12; int pt = (id / 12) % 8; int b = id / 96;
    int p0 = pt * 64, d0 = dt * 64;
    int tid = threadIdx.x;
    int w = tid >> 6, lane = tid & 63;
    int w_m = w & 1, w_n = w >> 1;
    int m_l = lane & 31, kg = lane >> 5;
    int r0 = tid >> 3, cc0 = tid & 7;
    int r1 = r0 + 32;
    if (tid < 64) {
        int bp = b * Pc + p0 + tid;
        maskS[tid] = (hts[bp * 2] + hts[bp * 2 + 1] != 0) ? 1.f : 0.f;
    }
    f16x8 ar0, ar1, br0, br1;
    auto loadt = [&](int it) {
        int k0 = it * 64;
        const float* A0 = ca + (size_t)(b * Pc + p0 + r0) * Lc + k0 + cc0 * 8;
        const float* A1 = ca + (size_t)(b * Pc + p0 + r1) * Lc + k0 + cc0 * 8;
#pragma unroll
        for (int j = 0; j < 8; ++j) { ar0[j] = (f16)A0[j]; ar1[j] = (f16)A1[j]; }
        br0 = *(const f16x8*)(ctxT + (size_t)(b * Dc + d0 + r0) * Lc + k0 + cc0 * 8);
        br1 = *(const f16x8*)(ctxT + (size_t)(b * Dc + d0 + r1) * Lc + k0 + cc0 * 8);
    };
    auto writet = [&](int p) {
        ((f16x8*)As[p])[r0 * 8 + (cc0 ^ (r0 & 7))] = ar0;
        ((f16x8*)As[p])[r1 * 8 + (cc0 ^ (r1 & 7))] = ar1;
        ((f16x8*)Bs[p])[r0 * 8 + (cc0 ^ (r0 & 7))] = br0;
        ((f16x8*)Bs[p])[r1 * 8 + (cc0 ^ (r1 & 7))] = br1;
    };
    loadt(0); writet(0); loadt(1);
    f32x16 acc;
#pragma unroll
    for (int i = 0; i < 16; ++i) acc[i] = 0.f;
    int ar = w_m * 32 + m_l;
    int br = w_n * 32 + m_l;
    for (int it = 0; it < 8; ++it) {
        int p = it & 1;
        __syncthreads();
        if (it < 7) writet(p ^ 1);
        if (it < 6) loadt(it + 2);
#pragma unroll
        for (int s = 0; s < 4; ++s) {
            int ck = s * 2 + kg;
            f16x8 a = ((const f16x8*)As[p])[ar * 8 + (ck ^ (ar & 7))];
            f16x8 bv = ((const f16x8*)Bs[p])[br * 8 + (ck ^ (br & 7))];
            acc = __builtin_amdgcn_mfma_f32_32x32x16_f16(a, bv, acc, 0, 0, 0);
        }
    }
#pragma unroll
    for (int reg = 0; reg < 16; ++reg) {
        int row = (reg & 3) + 8 * (reg >> 2) + 4 * kg;
        int p = p0 + w_m * 32 + row;
        int d = d0 + w_n * 32 + m_l;
        ci[(size_t)(b * Pc + p) * Dc + d] = (f16)(acc[reg] * maskS[w_m * 32 + row]);
    }
}

// ---------------- K10: MFMA proj merged (z=2), f16 ----------------
__global__ __launch_bounds__(256) void k_proj_mfma(const f16* __restrict__ Xh, const f16* __restrict__ Wh,
                                                   const float* __restrict__ bh,
                                                   const f16* __restrict__ Xt, const f16* __restrict__ Wt,
                                                   const float* __restrict__ bt,
                                                   const f16* __restrict__ Xc, const f16* __restrict__ Whc,
                                                   const float* __restrict__ bhc,
                                                   const f16* __restrict__ Wtc, const float* __restrict__ btc,
                                                   f16* __restrict__ outh, f16* __restrict__ outt) {
    __shared__ __align__(16) f16 Xs[2][64 * 64];
    __shared__ __align__(16) f16 Ws[2][64 * 64];
    int z = blockIdx.z;
    const f16* X1 = z ? Xt : Xh;
    const f16* W1 = z ? Wt : Wh;
    const float* b1 = z ? bt : bh;
    const f16* W2 = z ? Wtc : Whc;
    const float* b2 = z ? btc : bhc;
    f16* outp = z ? outt : outh;
    int m0 = blockIdx.x * 64, n0 = blockIdx.y * 64;
    int tid = threadIdx.x;
    int w = tid >> 6, lane = tid & 63;
    int w_m = w & 1, w_n = w >> 1;
    int m_l = lane & 31, kg = lane >> 5;
    const f16* Xarr[2] = {X1, Xc};
    const f16* Warr[2] = {W1, W2};
    int r0 = tid >> 3, cc0 = tid & 7;
    int r1 = r0 + 32;
    f16x8 xr0, xr1, wr0, wr1;
    auto loadt = [&](int it) {
        int src = it / 12; int k0 = (it % 12) * 64;
        const f16* X = Xarr[src]; const f16* W = Warr[src];
        xr0 = *(const f16x8*)(X + (size_t)(m0 + r0) * Dc + k0 + cc0 * 8);
        xr1 = *(const f16x8*)(X + (size_t)(m0 + r1) * Dc + k0 + cc0 * 8);
        wr0 = *(const f16x8*)(W + (size_t)(n0 + r0) * Dc + k0 + cc0 * 8);
        wr1 = *(const f16x8*)(W + (size_t)(n0 + r1) * Dc + k0 + cc0 * 8);
    };
    auto writet = [&](int p) {
        ((f16x8*)Xs[p])[r0 * 8 + (cc0 ^ (r0 & 7))] = xr0;
        ((f16x8*)Xs[p])[r1 * 8 + (cc0 ^ (r1 & 7))] = xr1;
        ((f16x8*)Ws[p])[r0 * 8 + (cc0 ^ (r0 & 7))] = wr0;
        ((f16x8*)Ws[p])[r1 * 8 + (cc0 ^ (r1 & 7))] = wr1;
    };
    loadt(0); writet(0); loadt(1);
    f32x16 acc;
#pragma unroll
    for (int i = 0; i < 16; ++i) acc[i] = 0.f;
    int ar = w_m * 32 + m_l;
    int br = w_n * 32 + m_l;
    for (int it = 0; it < 24; ++it) {
        int p = it & 1;
        __syncthreads();
        if (it < 23) writet(p ^ 1);
        if (it < 22) loadt(it + 2);
#pragma unroll
        for (int s = 0; s < 4; ++s) {
            int ck = s * 2 + kg;
            f16x8 a = ((const f16x8*)Xs[p])[ar * 8 + (ck ^ (ar & 7))];
            f16x8 b = ((const f16x8*)Ws[p])[br * 8 + (ck ^ (br & 7))];
            acc = __builtin_amdgcn_mfma_f32_32x32x16_f16(a, b, acc, 0, 0, 0);
        }
    }
#pragma unroll
    for (int reg = 0; reg < 16; ++reg) {
        int row = (reg & 3) + 8 * (reg >> 2) + 4 * kg;
        int m = m0 + w_m * 32 + row;
        int n = n0 + w_n * 32 + m_l;
        float v = tanhf(acc[reg] + b1[n] + b2[n]);
        outp[(size_t)m * Dc + n] = (f16)v;
    }
}

// ---------------- K11a: init out with bias ----------------
__global__ __launch_bounds__(256) void k_outinit(const float* __restrict__ cb, float* __restrict__ out) {
    int idx = blockIdx.x * 256 + threadIdx.x;
    if (idx < Bc * Pc * Rc) out[idx] = cb[idx % Rc];
}

// ---------------- K11b v5: group bilinear, 4 waves = (bp-half x r-half), acc 2x2, 3 blk/CU ----------------
__global__ __launch_bounds__(256, 3) void k_bilin5(const f16* __restrict__ hF, const f16* __restrict__ tF,
                                                   const f16* __restrict__ Wp, float* __restrict__ outp) {
    __shared__ __align__(16) f16 tS[128 * 64];   // [bp][(cc^(bp&7))*8+j]
    __shared__ f16 hS[128 * 17];                 // 16 chunk h values per bp
    int id = blockIdx.x;
    int tile = id / 48;
    int slice = id % 48;         // slice%8 -> XCD; 6 slices x 256KB Wp per XCD (L2-resident)
    int bp0 = tile * 128;
    int tid = threadIdx.x;
    int w = tid >> 6, lane = tid & 63;
    int w_m = w & 1, w_r = w >> 1;
    int m_l = lane & 31, kg = lane >> 5;
    int c0 = slice * 16;
    int n = c0 >> 6;             // 16-chunk slice never crosses a 64-chunk (n) boundary

    for (int idx = tid; idx < 128 * 16; idx += 256) {
        int bp = idx >> 4, i = idx & 15;
        hS[bp * 17 + i] = hF[(size_t)(bp0 + bp) * Dc + c0 + i];
    }
    for (int idx = tid; idx < 128 * 8; idx += 256) {
        int bp = idx >> 3, cc = idx & 7;
        f16x8 tv = *(const f16x8*)(tF + (size_t)(bp0 + bp) * Dc + n * 64 + cc * 8);
        ((f16x8*)tS)[bp * 8 + (cc ^ (bp & 7))] = tv;
    }
    __syncthreads();

    f32x16 acc[2][2];
#pragma unroll
    for (int mt = 0; mt < 2; ++mt)
#pragma unroll
        for (int rt = 0; rt < 2; ++rt)
#pragma unroll
            for (int i = 0; i < 16; ++i) acc[mt][rt][i] = 0.f;

    int rowA = w_m * 64 + m_l;
    int rowB = rowA + 32;
    const f16x8* WpB = (const f16x8*)Wp;

    for (int ii = 0; ii < 16; ++ii) {
        int cc = c0 + ii;
        f16 hv0 = hS[rowA * 17 + ii];
        f16 hv1 = hS[rowB * 17 + ii];
        const f16x8* wpb = WpB + (size_t)cc * 16 * 64 + lane;
#pragma unroll
        for (int s = 0; s < 4; ++s) {
            int ck = s * 2 + kg;
            f16x8 tv0 = ((const f16x8*)tS)[rowA * 8 + (ck ^ (rowA & 7))];
            f16x8 tv1 = ((const f16x8*)tS)[rowB * 8 + (ck ^ (rowB & 7))];
            f16x8 a0 = tv0 * hv0;
            f16x8 a1 = tv1 * hv1;
            f16x8 B0 = wpb[(s * 4 + 2 * w_r + 0) * 64];
            f16x8 B1 = wpb[(s * 4 + 2 * w_r + 1) * 64];
            acc[0][0] = __builtin_amdgcn_mfma_f32_32x32x16_f16(a0, B0, acc[0][0], 0, 0, 0);
            acc[1][0] = __builtin_amdgcn_mfma_f32_32x32x16_f16(a1, B0, acc[1][0], 0, 0, 0);
            acc[0][1] = __builtin_amdgcn_mfma_f32_32x32x16_f16(a0, B1, acc[0][1], 0, 0, 0);
            acc[1][1] = __builtin_amdgcn_mfma_f32_32x32x16_f16(a1, B1, acc[1][1], 0, 0, 0);
        }
    }

#pragma unroll
    for (int rt = 0; rt < 2; ++rt) {
        int r = (w_r * 2 + rt) * 32 + m_l;
        if (r < Rc) {
#pragma unroll
            for (int mt = 0; mt < 2; ++mt)
#pragma unroll
                for (int reg = 0; reg < 16; ++reg) {
                    int row = (reg & 3) + 8 * (reg >> 2) + 4 * kg;
                    int bp = bp0 + w_m * 64 + mt * 32 + row;
                    atomicAdd(&outp[(size_t)bp * Rc + r], acc[mt][rt][reg]);
                }
        }
    }
}

extern "C" void kernel_launch(void* const* d_in, const int* in_sizes, int n_in,
                              void* d_out, int out_size, void* d_ws, size_t ws_size,
                              hipStream_t stream) {
    const float* context   = (const float*)d_in[0];
    const float* attention = (const float*)d_in[1];
    const float* mm        = (const float*)d_in[2];
    const float* em        = (const float*)d_in[3];
    const int*   hts       = (const int*)d_in[4];
    const float* hW        = (const float*)d_in[5];
    const float* hb        = (const float*)d_in[6];
    const float* tW        = (const float*)d_in[7];
    const float* tb        = (const float*)d_in[8];
    const float* hcW       = (const float*)d_in[9];
    const float* hcb       = (const float*)d_in[10];
    const float* tcW       = (const float*)d_in[11];
    const float* tcb       = (const float*)d_in[12];
    const float* clasW     = (const float*)d_in[13];
    const float* clasb     = (const float*)d_in[14];
    float* out = (float*)d_out;

    char* wsb = (char*)d_ws;
    auto alloc = [&](size_t bytes) { char* p = wsb; wsb += (bytes + 255) & ~(size_t)255; return p; };
    float* mention     = (float*)alloc((size_t)Bc * Mc * Dc * 4);
    float* tmpML       = (float*)alloc((size_t)Bc * Mc * Lc * 4);
    float* entity_att  = (float*)alloc((size_t)Bc * Ec * Mc * 4);
    float* em_tok      = (float*)alloc((size_t)Bc * Ec * Lc * 4);
    float* ent_att     = (float*)alloc((size_t)Bc * Hc * Ec * Lc * 4);
    float* ctx_att     = (float*)alloc((size_t)Bc * Pc * Lc * 4);
    f16* h_buf   = (f16*)alloc((size_t)Bc * Pc * Dc * 2);
    f16* t_buf   = (f16*)alloc((size_t)Bc * Pc * Dc * 2);
    f16* ctxinfo = (f16*)alloc((size_t)Bc * Pc * Dc * 2);
    f16* h_fin   = (f16*)alloc((size_t)Bc * Pc * Dc * 2);
    f16* t_fin   = (f16*)alloc((size_t)Bc * Pc * Dc * 2);
    f16* hWb     = (f16*)alloc((size_t)Dc * Dc * 2);
    f16* tWb     = (f16*)alloc((size_t)Dc * Dc * 2);
    f16* hcWb    = (f16*)alloc((size_t)Dc * Dc * 2);
    f16* tcWb    = (f16*)alloc((size_t)Dc * Dc * 2);
    f16* ctxT    = (f16*)alloc((size_t)Bc * Dc * Lc * 2);
    f16* Wp      = (f16*)alloc((size_t)768 * 16 * 64 * 8 * 2);

    hipMemsetAsync(tmpML, 0, (size_t)Bc * Mc * Lc * 4, stream);
    k_prep<<<dim3(5504), dim3(256), 0, stream>>>(hW, tW, hcW, tcW, hWb, tWb, hcWb, tcWb,
                                                 clasW, Wp, context, ctxT);
    k_emtok<<<dim3(Bc * Ec), dim3(256), 0, stream>>>(em, mm, em_tok);
    k_attpass<<<dim3(Bc * Hc * 8), dim3(256), 0, stream>>>(mm, em_tok, attention, tmpML, ent_att);
    k_mention_mfma<<<dim3(Bc * 12), dim3(256), 0, stream>>>(mm, ctxT, mention);
    k_ment_ent<<<dim3(Bc * 4), dim3(256), 0, stream>>>(tmpML, mm, em, entity_att);
    k_htctx<<<dim3(Bc * Pc), dim3(256), 0, stream>>>(hts, em, entity_att, mention, ent_att,
                                                     h_buf, t_buf, ctx_att);
    k_ctxinfo_mfma<<<dim3(384), dim3(256), 0, stream>>>(hts, ctx_att, ctxT, ctxinfo);
    k_proj_mfma<<<dim3(32, 12, 2), dim3(256), 0, stream>>>(h_buf, hWb, hb, t_buf, tWb, tb,
                                                           ctxinfo, hcWb, hcb, tcWb, tcb, h_fin, t_fin);
    k_outinit<<<dim3((Bc * Pc * Rc + 255) / 256), dim3(256), 0, stream>>>(clasb, out);
    k_bilin5<<<dim3(768), dim3(256), 0, stream>>>(h_fin, t_fin, Wp, out);
}

// Round 7
// 355.762 us; speedup vs baseline: 1.2172x; 1.0996x over previous
//
#include <hip/hip_runtime.h>
#include <math.h>

#define Bc 4
#define Lc 512
#define Dc 768
#define Hc 12
#define Mc 48
#define Ec 32
#define Pc 512
#define Rc 97
#define MINV 1e-30f

typedef _Float16 f16;
typedef __attribute__((ext_vector_type(8))) _Float16 f16x8;
typedef __attribute__((ext_vector_type(4))) _Float16 f16x4;
typedef __attribute__((ext_vector_type(16))) float f32x16;

// ---------------- K_prep: fused cvt4 (weights->f16) + wprep (clasW swizzle) + tran (ctx transpose) ----------------
__global__ __launch_bounds__(256) void k_prep(const float* __restrict__ hW, const float* __restrict__ tW,
                                              const float* __restrict__ hcW, const float* __restrict__ tcW,
                                              f16* __restrict__ hWb, f16* __restrict__ tWb,
                                              f16* __restrict__ hcWb, f16* __restrict__ tcWb,
                                              const float* __restrict__ clasW, f16* __restrict__ Wp,
                                              const float* __restrict__ ctx, f16* __restrict__ ctxT) {
    __shared__ f16 Ts[64][72];
    int bid = blockIdx.x;
    int tid = threadIdx.x;
    if (bid < 2048) {
        const int DD = Dc * Dc;
        int i = bid * 256 + tid;
        int stride = 2048 * 256;
        for (; i < 4 * DD; i += stride) {
            int sel = i / DD, j = i % DD;
            const float* s = (sel == 0) ? hW : (sel == 1) ? tW : (sel == 2) ? hcW : tcW;
            f16* d = (sel == 0) ? hWb : (sel == 1) ? tWb : (sel == 2) ? hcWb : tcWb;
            d[j] = (f16)s[j];
        }
    } else if (bid < 5120) {
        int gid = (bid - 2048) * 256 + tid;   // < 768*16*64
        int lane = gid & 63; int f = gid >> 6;
        int rt = f & 3; int s = (f >> 2) & 3; int c = f >> 4;
        int n_l = lane & 31, kg = lane >> 5;
        int r = rt * 32 + n_l;
        f16x8 v;
        if (r < Rc) {
            const float* src = clasW + (size_t)r * (Dc * 64) + c * 64 + s * 16 + kg * 8;
#pragma unroll
            for (int j = 0; j < 8; ++j) v[j] = (f16)src[j];
        } else {
#pragma unroll
            for (int j = 0; j < 8; ++j) v[j] = (f16)0.f;
        }
        ((f16x8*)Wp)[gid] = v;
    } else {
        int id = bid - 5120;           // ((b*8+lt)*12+dt)
        int dt = id % 12; int lt = (id / 12) % 8; int b = id / 96;
        int l0 = lt * 64, d0 = dt * 64;
        int r = tid >> 2, cg = tid & 3;
        const float* src = ctx + ((size_t)b * Lc + l0 + r) * Dc + d0 + cg * 16;
#pragma unroll
        for (int u = 0; u < 4; ++u) {
            float4 v = ((const float4*)src)[u];
            Ts[cg * 16 + u * 4 + 0][r] = (f16)v.x;
            Ts[cg * 16 + u * 4 + 1][r] = (f16)v.y;
            Ts[cg * 16 + u * 4 + 2][r] = (f16)v.z;
            Ts[cg * 16 + u * 4 + 3][r] = (f16)v.w;
        }
        __syncthreads();
        int dr = tid >> 2, seg = tid & 3;
        f16* dst = ctxT + ((size_t)b * Dc + d0 + dr) * Lc + l0 + seg * 16;
        f16x8 o0, o1;
#pragma unroll
        for (int j = 0; j < 8; ++j) { o0[j] = Ts[dr][seg * 16 + j]; o1[j] = Ts[dr][seg * 16 + 8 + j]; }
        *(f16x8*)dst = o0;
        *(f16x8*)(dst + 8) = o1;
    }
}

// ---------------- K1: mention = mm @ ctx via MFMA ----------------
__global__ __launch_bounds__(256) void k_mention_mfma(const float* __restrict__ mm,
                                                      const f16* __restrict__ ctxT,
                                                      float* __restrict__ mention) {
    __shared__ __align__(16) f16 As[2][64 * 64];
    __shared__ __align__(16) f16 Bs[2][64 * 64];
    int id = blockIdx.x;            // b*12+dt
    int dt = id % 12; int b = id / 12;
    int d0 = dt * 64;
    int tid = threadIdx.x;
    int w = tid >> 6, lane = tid & 63;
    int w_m = w & 1, w_n = w >> 1;
    int m_l = lane & 31, kg = lane >> 5;
    int r0 = tid >> 3, cc0 = tid & 7;
    int r1 = r0 + 32;
    int mr0 = (r0 < Mc) ? r0 : r0 - Mc;
    int mr1 = (r1 < Mc) ? r1 : r1 - Mc;
    f16x8 ar0, ar1, br0, br1;
    auto loadt = [&](int it) {
        int k0 = it * 64;
        const float* A0 = mm + ((size_t)b * Mc + mr0) * Lc + k0 + cc0 * 8;
        const float* A1 = mm + ((size_t)b * Mc + mr1) * Lc + k0 + cc0 * 8;
#pragma unroll
        for (int j = 0; j < 8; ++j) { ar0[j] = (f16)A0[j]; ar1[j] = (f16)A1[j]; }
        br0 = *(const f16x8*)(ctxT + ((size_t)b * Dc + d0 + r0) * Lc + k0 + cc0 * 8);
        br1 = *(const f16x8*)(ctxT + ((size_t)b * Dc + d0 + r1) * Lc + k0 + cc0 * 8);
    };
    auto writet = [&](int p) {
        ((f16x8*)As[p])[r0 * 8 + (cc0 ^ (r0 & 7))] = ar0;
        ((f16x8*)As[p])[r1 * 8 + (cc0 ^ (r1 & 7))] = ar1;
        ((f16x8*)Bs[p])[r0 * 8 + (cc0 ^ (r0 & 7))] = br0;
        ((f16x8*)Bs[p])[r1 * 8 + (cc0 ^ (r1 & 7))] = br1;
    };
    loadt(0); writet(0); loadt(1);
    f32x16 acc;
#pragma unroll
    for (int i = 0; i < 16; ++i) acc[i] = 0.f;
    int ar = w_m * 32 + m_l;
    int br = w_n * 32 + m_l;
    for (int it = 0; it < 8; ++it) {
        int p = it & 1;
        __syncthreads();
        if (it < 7) writet(p ^ 1);
        if (it < 6) loadt(it + 2);
#pragma unroll
        for (int s = 0; s < 4; ++s) {
            int ck = s * 2 + kg;
            f16x8 a = ((const f16x8*)As[p])[ar * 8 + (ck ^ (ar & 7))];
            f16x8 bv = ((const f16x8*)Bs[p])[br * 8 + (ck ^ (br & 7))];
            acc = __builtin_amdgcn_mfma_f32_32x32x16_f16(a, bv, acc, 0, 0, 0);
        }
    }
#pragma unroll
    for (int reg = 0; reg < 16; ++reg) {
        int row = (reg & 3) + 8 * (reg >> 2) + 4 * kg;
        int m = w_m * 32 + row;
        if (m < Mc) mention[((size_t)b * Mc + m) * Dc + d0 + w_n * 32 + m_l] = acc[reg];
    }
}

// ---------------- K2 fused: one pass over attention ----------------
__global__ __launch_bounds__(256) void k_attpass(const float* __restrict__ mm,
                                                 const float* __restrict__ emt,
                                                 const float* __restrict__ att,
                                                 float* __restrict__ tmpML,
                                                 float* __restrict__ eat) {
    __shared__ __align__(16) f16 Ss[96 * 64];
    __shared__ __align__(16) f16 attS[64 * 64];
    int id = blockIdx.x;
    int mt = id & 7; int bh = id >> 3;
    int b = bh / Hc, h = bh % Hc;
    int m0 = mt * 64;
    int tid = threadIdx.x;
    int w = tid >> 6, lane = tid & 63;
    int n_l = lane & 31, kg = lane >> 5;

    const float* ab = att + (size_t)bh * Lc * Lc + m0;
    int mRow = tid & 63, lg = tid >> 6;
    float pre[16];
#pragma unroll
    for (int q = 0; q < 16; ++q) pre[q] = ab[(size_t)(lg * 16 + q) * Lc + mRow];

    f32x16 acc[2];
#pragma unroll
    for (int nt = 0; nt < 2; ++nt)
#pragma unroll
        for (int i = 0; i < 16; ++i) acc[nt][i] = 0.f;

    for (int kc = 0; kc < 8; ++kc) {
        __syncthreads();
#pragma unroll
        for (int half = 0; half < 2; ++half) {
            int cc = lg * 2 + half;
            f16x8 v;
#pragma unroll
            for (int jj = 0; jj < 8; ++jj) v[jj] = (f16)pre[half * 8 + jj];
            ((f16x8*)attS)[mRow * 8 + (cc ^ (mRow & 7))] = v;
        }
#pragma unroll
        for (int k = 0; k < 3; ++k) {
            int idx = tid + k * 256;
            int row = idx >> 3, cc = idx & 7;
            f16x8 v;
            if (row < Mc) {
                const float* src = mm + ((size_t)b * Mc + row) * Lc + kc * 64 + cc * 8;
#pragma unroll
                for (int j = 0; j < 8; ++j) v[j] = (f16)src[j];
            } else if (row < 80) {
                const float* src = emt + ((size_t)b * Ec + row - Mc) * Lc + kc * 64 + cc * 8;
#pragma unroll
                for (int j = 0; j < 8; ++j) v[j] = (f16)src[j];
            } else {
#pragma unroll
                for (int j = 0; j < 8; ++j) v[j] = (f16)0.f;
            }
            ((f16x8*)Ss)[row * 8 + (cc ^ (row & 7))] = v;
        }
        if (kc < 7) {
#pragma unroll
            for (int q = 0; q < 16; ++q)
                pre[q] = ab[(size_t)((kc + 1) * 64 + lg * 16 + q) * Lc + mRow];
        }
        __syncthreads();
        if (w < 3) {
            int arow = w * 32 + n_l;
#pragma unroll
            for (int kk = 0; kk < 4; ++kk) {
                int cc = kk * 2 + kg;
                f16x8 a = ((const f16x8*)Ss)[arow * 8 + (cc ^ (arow & 7))];
#pragma unroll
                for (int nt = 0; nt < 2; ++nt) {
                    int bcol = nt * 32 + n_l;
                    f16x8 bb = ((const f16x8*)attS)[bcol * 8 + (cc ^ (bcol & 7))];
                    acc[nt] = __builtin_amdgcn_mfma_f32_32x32x16_f16(a, bb, acc[nt], 0, 0, 0);
                }
            }
        }
    }
    if (w < 3) {
#pragma unroll
        for (int nt = 0; nt < 2; ++nt)
#pragma unroll
            for (int reg = 0; reg < 16; ++reg) {
                int row = (reg & 3) + 8 * (reg >> 2) + 4 * kg;
                int rr = w * 32 + row;
                int col = m0 + nt * 32 + n_l;
                if (rr < Mc) {
                    atomicAdd(&tmpML[((size_t)b * Mc + rr) * Lc + col], acc[nt][reg]);
                } else if (rr < 80) {
                    eat[(((size_t)b * Hc + h) * Ec + (rr - Mc)) * Lc + col] = acc[nt][reg];
                }
            }
    }
}

// ---------------- K3 fused: mention_att (LDS only) + entity_att ----------------
__global__ __launch_bounds__(256) void k_ment_ent(const float* __restrict__ tmp,
                                                  const float* __restrict__ mm,
                                                  const float* __restrict__ em,
                                                  float* __restrict__ ea) {
    __shared__ float maS[Mc][12];
    int b = blockIdx.x >> 2, q = blockIdx.x & 3;
    int tid = threadIdx.x;
    for (int idx = tid; idx < Mc * 12; idx += 256) {
        int m = idx / 12, m2 = q * 12 + idx % 12;
        float acc = 0.f;
        const float* t = tmp + (size_t)(b * Mc + m) * Lc;
        const float* r = mm + (size_t)(b * Mc + m2) * Lc;
        for (int j = 0; j < Lc; ++j) acc += t[j] * r[j];
        maS[m][idx % 12] = acc;
    }
    __syncthreads();
    for (int idx = tid; idx < Ec * 12; idx += 256) {
        int e = idx / 12, m2q = idx % 12;
        float acc = 0.f;
        const float* emr = em + (size_t)(b * Ec + e) * Mc;
        for (int m = 0; m < Mc; ++m) acc += emr[m] * maS[m][m2q];
        ea[((size_t)b * Ec + e) * Mc + q * 12 + m2q] = acc;
    }
}

// ---------------- K5 fused: ctx_att + h/t build, per bp ----------------
__global__ __launch_bounds__(256) void k_htctx(const int* __restrict__ hts,
                                               const float* __restrict__ em,
                                               const float* __restrict__ ea,
                                               const float* __restrict__ mention,
                                               const float* __restrict__ eat,
                                               f16* __restrict__ hB, f16* __restrict__ tB,
                                               float* __restrict__ ca) {
    int bp = blockIdx.x; int b = bp / Pc;
    int hi = hts[bp * 2], ti = hts[bp * 2 + 1];
    float mask = (hi + ti != 0) ? 1.f : 0.f;
    int tid = threadIdx.x;
    __shared__ float red[256];
    __shared__ float inv;
    __shared__ float hat[Mc], tat[Mc];
    __shared__ float sums[2];

    float a0 = 0.f, a1 = 0.f;
    for (int h = 0; h < Hc; ++h) {
        const float* ph = eat + ((size_t)(b * Hc + h) * Ec + hi) * Lc;
        const float* pt = eat + ((size_t)(b * Hc + h) * Ec + ti) * Lc;
        a0 += ph[tid] * pt[tid];
        a1 += ph[tid + 256] * pt[tid + 256];
    }
    red[tid] = a0 + a1;
    __syncthreads();
    for (int s = 128; s > 0; s >>= 1) { if (tid < s) red[tid] += red[tid + s]; __syncthreads(); }
    if (tid == 0) inv = 1.f / (red[0] + MINV);
    if (tid < Mc) {
        float hm = em[(size_t)(b * Ec + hi) * Mc + tid];
        float tm = em[(size_t)(b * Ec + ti) * Mc + tid];
        float eh = ea[(size_t)(b * Ec + hi) * Mc + tid];
        float et = ea[(size_t)(b * Ec + ti) * Mc + tid];
        hat[tid] = eh * tm * mask;
        tat[tid] = et * hm * mask;
    }
    __syncthreads();
    ca[(size_t)bp * Lc + tid] = a0 * inv;
    ca[(size_t)bp * Lc + tid + 256] = a1 * inv;
    if (tid == 0) {
        float sh = 0.f, st = 0.f;
        for (int m = 0; m < Mc; ++m) { sh += hat[m]; st += tat[m]; }
        sums[0] = 1.f / (sh + MINV);
        sums[1] = 1.f / (st + MINV);
    }
    __syncthreads();
    float hnorm = sums[0], tnorm = sums[1];
    for (int d = tid; d < Dc; d += 256) {
        float ah = 0.f, at = 0.f;
        const float* mb = mention + (size_t)b * Mc * Dc + d;
        for (int m = 0; m < Mc; ++m) {
            float mv = mb[(size_t)m * Dc];
            ah += tat[m] * mv;
            at += hat[m] * mv;
        }
        hB[(size_t)bp * Dc + d] = (f16)(ah * tnorm * mask);
        tB[(size_t)bp * Dc + d] = (f16)(at * hnorm * mask);
    }
}

// ---------------- K6: em_tok[b,e,l] normalized ----------------
__global__ __launch_bounds__(256) void k_emtok(const float* __restrict__ em,
                                               const float* __restrict__ mm,
                                               float* __restrict__ emt) {
    int be = blockIdx.x; int b = be / Ec;
    __shared__ float row[Mc];
    __shared__ float red[256];
    __shared__ float inv;
    int tid = threadIdx.x;
    if (tid < Mc) row[tid] = em[(size_t)be * Mc + tid];
    __syncthreads();
    float v0 = 0.f, v1 = 0.f;
    {
        const float* mb0 = mm + (size_t)b * Mc * Lc + tid;
        const float* mb1 = mm + (size_t)b * Mc * Lc + tid + 256;
        for (int m = 0; m < Mc; ++m) {
            v0 += row[m] * mb0[(size_t)m * Lc];
            v1 += row[m] * mb1[(size_t)m * Lc];
        }
    }
    red[tid] = v0 + v1;
    __syncthreads();
    for (int s = 128; s > 0; s >>= 1) { if (tid < s) red[tid] += red[tid + s]; __syncthreads(); }
    if (tid == 0) inv = 1.f / (red[0] + MINV);
    __syncthreads();
    emt[(size_t)be * Lc + tid] = v0 * inv;
    emt[(size_t)be * Lc + tid + 256] = v1 * inv;
}

// ---------------- K9: context_info via MFMA (f16) ----------------
__global__ __launch_bounds__(256) void k_ctxinfo_mfma(const int* __restrict__ hts,
                                                      const float* __restrict__ ca,
                                                      const f16* __restrict__ ctxT,
                                                      f16* __restrict__ ci) {
    __shared__ __align__(16) f16 As[2][64 * 64];
    __shared__ __align__(16) f16 Bs[2][64 * 64];
    __shared__ float maskS[64];
    int id = blockIdx.x;            // ((b*8+pt)*12+dt)
    int dt = id % 12; int pt = (id / 12) % 8; int b = id / 96;
    int p0 = pt * 64, d0 = dt * 64;
    int tid = threadIdx.x;
    int w = tid >> 6, lane = tid & 63;
    int w_m = w & 1, w_n = w >> 1;
    int m_l = lane & 31, kg = lane >> 5;
    int r0 = tid >> 3, cc0 = tid & 7;
    int r1 = r0 + 32;
    if (tid < 64) {
        int bp = b * Pc + p0 + tid;
        maskS[tid] = (hts[bp * 2] + hts[bp * 2 + 1] != 0) ? 1.f : 0.f;
    }
    f16x8 ar0, ar1, br0, br1;
    auto loadt = [&](int it) {
        int k0 = it * 64;
        const float* A0 = ca + (size_t)(b * Pc + p0 + r0) * Lc + k0 + cc0 * 8;
        const float* A1 = ca + (size_t)(b * Pc + p0 + r1) * Lc + k0 + cc0 * 8;
#pragma unroll
        for (int j = 0; j < 8; ++j) { ar0[j] = (f16)A0[j]; ar1[j] = (f16)A1[j]; }
        br0 = *(const f16x8*)(ctxT + (size_t)(b * Dc + d0 + r0) * Lc + k0 + cc0 * 8);
        br1 = *(const f16x8*)(ctxT + (size_t)(b * Dc + d0 + r1) * Lc + k0 + cc0 * 8);
    };
    auto writet = [&](int p) {
        ((f16x8*)As[p])[r0 * 8 + (cc0 ^ (r0 & 7))] = ar0;
        ((f16x8*)As[p])[r1 * 8 + (cc0 ^ (r1 & 7))] = ar1;
        ((f16x8*)Bs[p])[r0 * 8 + (cc0 ^ (r0 & 7))] = br0;
        ((f16x8*)Bs[p])[r1 * 8 + (cc0 ^ (r1 & 7))] = br1;
    };
    loadt(0); writet(0); loadt(1);
    f32x16 acc;
#pragma unroll
    for (int i = 0; i < 16; ++i) acc[i] = 0.f;
    int ar = w_m * 32 + m_l;
    int br = w_n * 32 + m_l;
    for (int it = 0; it < 8; ++it) {
        int p = it & 1;
        __syncthreads();
        if (it < 7) writet(p ^ 1);
        if (it < 6) loadt(it + 2);
#pragma unroll
        for (int s = 0; s < 4; ++s) {
            int ck = s * 2 + kg;
            f16x8 a = ((const f16x8*)As[p])[ar * 8 + (ck ^ (ar & 7))];
            f16x8 bv = ((const f16x8*)Bs[p])[br * 8 + (ck ^ (br & 7))];
            acc = __builtin_amdgcn_mfma_f32_32x32x16_f16(a, bv, acc, 0, 0, 0);
        }
    }
#pragma unroll
    for (int reg = 0; reg < 16; ++reg) {
        int row = (reg & 3) + 8 * (reg >> 2) + 4 * kg;
        int p = p0 + w_m * 32 + row;
        int d = d0 + w_n * 32 + m_l;
        ci[(size_t)(b * Pc + p) * Dc + d] = (f16)(acc[reg] * maskS[w_m * 32 + row]);
    }
}

// ---------------- K10: MFMA proj merged (z=2), f16 ----------------
__global__ __launch_bounds__(256) void k_proj_mfma(const f16* __restrict__ Xh, const f16* __restrict__ Wh,
                                                   const float* __restrict__ bh,
                                                   const f16* __restrict__ Xt, const f16* __restrict__ Wt,
                                                   const float* __restrict__ bt,
                                                   const f16* __restrict__ Xc, const f16* __restrict__ Whc,
                                                   const float* __restrict__ bhc,
                                                   const f16* __restrict__ Wtc, const float* __restrict__ btc,
                                                   f16* __restrict__ outh, f16* __restrict__ outt) {
    __shared__ __align__(16) f16 Xs[2][64 * 64];
    __shared__ __align__(16) f16 Ws[2][64 * 64];
    int z = blockIdx.z;
    const f16* X1 = z ? Xt : Xh;
    const f16* W1 = z ? Wt : Wh;
    const float* b1 = z ? bt : bh;
    const f16* W2 = z ? Wtc : Whc;
    const float* b2 = z ? btc : bhc;
    f16* outp = z ? outt : outh;
    int m0 = blockIdx.x * 64, n0 = blockIdx.y * 64;
    int tid = threadIdx.x;
    int w = tid >> 6, lane = tid & 63;
    int w_m = w & 1, w_n = w >> 1;
    int m_l = lane & 31, kg = lane >> 5;
    const f16* Xarr[2] = {X1, Xc};
    const f16* Warr[2] = {W1, W2};
    int r0 = tid >> 3, cc0 = tid & 7;
    int r1 = r0 + 32;
    f16x8 xr0, xr1, wr0, wr1;
    auto loadt = [&](int it) {
        int src = it / 12; int k0 = (it % 12) * 64;
        const f16* X = Xarr[src]; const f16* W = Warr[src];
        xr0 = *(const f16x8*)(X + (size_t)(m0 + r0) * Dc + k0 + cc0 * 8);
        xr1 = *(const f16x8*)(X + (size_t)(m0 + r1) * Dc + k0 + cc0 * 8);
        wr0 = *(const f16x8*)(W + (size_t)(n0 + r0) * Dc + k0 + cc0 * 8);
        wr1 = *(const f16x8*)(W + (size_t)(n0 + r1) * Dc + k0 + cc0 * 8);
    };
    auto writet = [&](int p) {
        ((f16x8*)Xs[p])[r0 * 8 + (cc0 ^ (r0 & 7))] = xr0;
        ((f16x8*)Xs[p])[r1 * 8 + (cc0 ^ (r1 & 7))] = xr1;
        ((f16x8*)Ws[p])[r0 * 8 + (cc0 ^ (r0 & 7))] = wr0;
        ((f16x8*)Ws[p])[r1 * 8 + (cc0 ^ (r1 & 7))] = wr1;
    };
    loadt(0); writet(0); loadt(1);
    f32x16 acc;
#pragma unroll
    for (int i = 0; i < 16; ++i) acc[i] = 0.f;
    int ar = w_m * 32 + m_l;
    int br = w_n * 32 + m_l;
    for (int it = 0; it < 24; ++it) {
        int p = it & 1;
        __syncthreads();
        if (it < 23) writet(p ^ 1);
        if (it < 22) loadt(it + 2);
#pragma unroll
        for (int s = 0; s < 4; ++s) {
            int ck = s * 2 + kg;
            f16x8 a = ((const f16x8*)Xs[p])[ar * 8 + (ck ^ (ar & 7))];
            f16x8 b = ((const f16x8*)Ws[p])[br * 8 + (ck ^ (br & 7))];
            acc = __builtin_amdgcn_mfma_f32_32x32x16_f16(a, b, acc, 0, 0, 0);
        }
    }
#pragma unroll
    for (int reg = 0; reg < 16; ++reg) {
        int row = (reg & 3) + 8 * (reg >> 2) + 4 * kg;
        int m = m0 + w_m * 32 + row;
        int n = n0 + w_n * 32 + m_l;
        float v = tanhf(acc[reg] + b1[n] + b2[n]);
        outp[(size_t)m * Dc + n] = (f16)v;
    }
}

// ---------------- K11b v6: group bilinear, partials via plain stores (no atomics) ----------------
__global__ __launch_bounds__(256, 3) void k_bilin6(const f16* __restrict__ hF, const f16* __restrict__ tF,
                                                   const f16* __restrict__ Wp, f16* __restrict__ partial) {
    __shared__ __align__(16) f16 tS[128 * 64];
    __shared__ f16 hS[128 * 17];
    int id = blockIdx.x;
    int tile = id / 48;
    int slice = id % 48;         // slice%8 -> XCD; 6 slices x 256KB Wp per XCD
    int bp0 = tile * 128;
    int tid = threadIdx.x;
    int w = tid >> 6, lane = tid & 63;
    int w_m = w & 1, w_r = w >> 1;
    int m_l = lane & 31, kg = lane >> 5;
    int c0 = slice * 16;
    int n = c0 >> 6;

    for (int idx = tid; idx < 128 * 16; idx += 256) {
        int bp = idx >> 4, i = idx & 15;
        hS[bp * 17 + i] = hF[(size_t)(bp0 + bp) * Dc + c0 + i];
    }
    for (int idx = tid; idx < 128 * 8; idx += 256) {
        int bp = idx >> 3, cc = idx & 7;
        f16x8 tv = *(const f16x8*)(tF + (size_t)(bp0 + bp) * Dc + n * 64 + cc * 8);
        ((f16x8*)tS)[bp * 8 + (cc ^ (bp & 7))] = tv;
    }
    __syncthreads();

    f32x16 acc[2][2];
#pragma unroll
    for (int mt = 0; mt < 2; ++mt)
#pragma unroll
        for (int rt = 0; rt < 2; ++rt)
#pragma unroll
            for (int i = 0; i < 16; ++i) acc[mt][rt][i] = 0.f;

    int rowA = w_m * 64 + m_l;
    int rowB = rowA + 32;
    const f16x8* WpB = (const f16x8*)Wp;

    for (int ii = 0; ii < 16; ++ii) {
        int cc = c0 + ii;
        const f16x8* wpb = WpB + (size_t)cc * 16 * 64 + lane;
        // hoist all 8 B-frag loads for this chunk to the top (one latency exposure per ii)
        f16x8 Bf[8];
#pragma unroll
        for (int s = 0; s < 4; ++s) {
            Bf[s * 2 + 0] = wpb[(s * 4 + 2 * w_r + 0) * 64];
            Bf[s * 2 + 1] = wpb[(s * 4 + 2 * w_r + 1) * 64];
        }
        f16 hv0 = hS[rowA * 17 + ii];
        f16 hv1 = hS[rowB * 17 + ii];
#pragma unroll
        for (int s = 0; s < 4; ++s) {
            int ck = s * 2 + kg;
            f16x8 tv0 = ((const f16x8*)tS)[rowA * 8 + (ck ^ (rowA & 7))];
            f16x8 tv1 = ((const f16x8*)tS)[rowB * 8 + (ck ^ (rowB & 7))];
            f16x8 a0 = tv0 * hv0;
            f16x8 a1 = tv1 * hv1;
            acc[0][0] = __builtin_amdgcn_mfma_f32_32x32x16_f16(a0, Bf[s * 2 + 0], acc[0][0], 0, 0, 0);
            acc[1][0] = __builtin_amdgcn_mfma_f32_32x32x16_f16(a1, Bf[s * 2 + 0], acc[1][0], 0, 0, 0);
            acc[0][1] = __builtin_amdgcn_mfma_f32_32x32x16_f16(a0, Bf[s * 2 + 1], acc[0][1], 0, 0, 0);
            acc[1][1] = __builtin_amdgcn_mfma_f32_32x32x16_f16(a1, Bf[s * 2 + 1], acc[1][1], 0, 0, 0);
        }
    }

    // plain f16 stores to partial[slice][bp][r]
    f16* pbase = partial + (size_t)slice * (2048 * 128);
#pragma unroll
    for (int rt = 0; rt < 2; ++rt) {
        int r = (w_r * 2 + rt) * 32 + m_l;
#pragma unroll
        for (int mt = 0; mt < 2; ++mt)
#pragma unroll
            for (int reg = 0; reg < 16; ++reg) {
                int row = (reg & 3) + 8 * (reg >> 2) + 4 * kg;
                int bp = bp0 + w_m * 64 + mt * 32 + row;
                pbase[(size_t)bp * 128 + r] = (f16)acc[mt][rt][reg];
            }
    }
}

// ---------------- K12: reduce partials + bias -> out ----------------
__global__ __launch_bounds__(256) void k_reduce(const f16* __restrict__ partial,
                                                const float* __restrict__ cb,
                                                float* __restrict__ out) {
    int idx = blockIdx.x * 256 + threadIdx.x;   // < 2048*32 (f16x4 chunks)
    int bp = idx >> 5, c = idx & 31;
    const f16x4* p = (const f16x4*)partial + idx;
    float a0 = 0.f, a1 = 0.f, a2 = 0.f, a3 = 0.f;
#pragma unroll
    for (int s = 0; s < 48; ++s) {
        f16x4 v = p[(size_t)s * (2048 * 32)];
        a0 += (float)v[0]; a1 += (float)v[1]; a2 += (float)v[2]; a3 += (float)v[3];
    }
    int rb = c * 4;
    float* ob = out + (size_t)bp * Rc;
    if (rb + 0 < Rc) ob[rb + 0] = a0 + cb[rb + 0];
    if (rb + 1 < Rc) ob[rb + 1] = a1 + cb[rb + 1];
    if (rb + 2 < Rc) ob[rb + 2] = a2 + cb[rb + 2];
    if (rb + 3 < Rc) ob[rb + 3] = a3 + cb[rb + 3];
}

extern "C" void kernel_launch(void* const* d_in, const int* in_sizes, int n_in,
                              void* d_out, int out_size, void* d_ws, size_t ws_size,
                              hipStream_t stream) {
    const float* context   = (const float*)d_in[0];
    const float* attention = (const float*)d_in[1];
    const float* mm        = (const float*)d_in[2];
    const float* em        = (const float*)d_in[3];
    const int*   hts       = (const int*)d_in[4];
    const float* hW        = (const float*)d_in[5];
    const float* hb        = (const float*)d_in[6];
    const float* tW        = (const float*)d_in[7];
    const float* tb        = (const float*)d_in[8];
    const float* hcW       = (const float*)d_in[9];
    const float* hcb       = (const float*)d_in[10];
    const float* tcW       = (const float*)d_in[11];
    const float* tcb       = (const float*)d_in[12];
    const float* clasW     = (const float*)d_in[13];
    const float* clasb     = (const float*)d_in[14];
    float* out = (float*)d_out;

    char* wsb = (char*)d_ws;
    auto alloc = [&](size_t bytes) { char* p = wsb; wsb += (bytes + 255) & ~(size_t)255; return p; };
    float* mention     = (float*)alloc((size_t)Bc * Mc * Dc * 4);
    float* tmpML       = (float*)alloc((size_t)Bc * Mc * Lc * 4);
    float* entity_att  = (float*)alloc((size_t)Bc * Ec * Mc * 4);
    float* em_tok      = (float*)alloc((size_t)Bc * Ec * Lc * 4);
    float* ent_att     = (float*)alloc((size_t)Bc * Hc * Ec * Lc * 4);
    float* ctx_att     = (float*)alloc((size_t)Bc * Pc * Lc * 4);
    f16* h_buf   = (f16*)alloc((size_t)Bc * Pc * Dc * 2);
    f16* t_buf   = (f16*)alloc((size_t)Bc * Pc * Dc * 2);
    f16* ctxinfo = (f16*)alloc((size_t)Bc * Pc * Dc * 2);
    f16* h_fin   = (f16*)alloc((size_t)Bc * Pc * Dc * 2);
    f16* t_fin   = (f16*)alloc((size_t)Bc * Pc * Dc * 2);
    f16* hWb     = (f16*)alloc((size_t)Dc * Dc * 2);
    f16* tWb     = (f16*)alloc((size_t)Dc * Dc * 2);
    f16* hcWb    = (f16*)alloc((size_t)Dc * Dc * 2);
    f16* tcWb    = (f16*)alloc((size_t)Dc * Dc * 2);
    f16* ctxT    = (f16*)alloc((size_t)Bc * Dc * Lc * 2);
    f16* Wp      = (f16*)alloc((size_t)768 * 16 * 64 * 8 * 2);
    f16* partial = (f16*)alloc((size_t)48 * 2048 * 128 * 2);   // 25.2 MB

    hipMemsetAsync(tmpML, 0, (size_t)Bc * Mc * Lc * 4, stream);
    k_prep<<<dim3(5504), dim3(256), 0, stream>>>(hW, tW, hcW, tcW, hWb, tWb, hcWb, tcWb,
                                                 clasW, Wp, context, ctxT);
    k_emtok<<<dim3(Bc * Ec), dim3(256), 0, stream>>>(em, mm, em_tok);
    k_attpass<<<dim3(Bc * Hc * 8), dim3(256), 0, stream>>>(mm, em_tok, attention, tmpML, ent_att);
    k_mention_mfma<<<dim3(Bc * 12), dim3(256), 0, stream>>>(mm, ctxT, mention);
    k_ment_ent<<<dim3(Bc * 4), dim3(256), 0, stream>>>(tmpML, mm, em, entity_att);
    k_htctx<<<dim3(Bc * Pc), dim3(256), 0, stream>>>(hts, em, entity_att, mention, ent_att,
                                                     h_buf, t_buf, ctx_att);
    k_ctxinfo_mfma<<<dim3(384), dim3(256), 0, stream>>>(hts, ctx_att, ctxT, ctxinfo);
    k_proj_mfma<<<dim3(32, 12, 2), dim3(256), 0, stream>>>(h_buf, hWb, hb, t_buf, tWb, tb,
                                                           ctxinfo, hcWb, hcb, tcWb, tcb, h_fin, t_fin);
    k_bilin6<<<dim3(768), dim3(256), 0, stream>>>(h_fin, t_fin, Wp, partial);
    k_reduce<<<dim3(256), dim3(256), 0, stream>>>(partial, clasb, out);
}

// Round 8
// 313.548 us; speedup vs baseline: 1.3811x; 1.1346x over previous
//
#include <hip/hip_runtime.h>
#include <math.h>

#define Bc 4
#define Lc 512
#define Dc 768
#define Hc 12
#define Mc 48
#define Ec 32
#define Pc 512
#define Rc 97
#define MINV 1e-30f

typedef _Float16 f16;
typedef __attribute__((ext_vector_type(8))) _Float16 f16x8;
typedef __attribute__((ext_vector_type(4))) _Float16 f16x4;
typedef __attribute__((ext_vector_type(16))) float f32x16;

// ---------------- K_prep: fused cvt4 (weights->f16) + wprep (clasW swizzle) + tran (ctx transpose) ----------------
__global__ __launch_bounds__(256) void k_prep(const float* __restrict__ hW, const float* __restrict__ tW,
                                              const float* __restrict__ hcW, const float* __restrict__ tcW,
                                              f16* __restrict__ hWb, f16* __restrict__ tWb,
                                              f16* __restrict__ hcWb, f16* __restrict__ tcWb,
                                              const float* __restrict__ clasW, f16* __restrict__ Wp,
                                              const float* __restrict__ ctx, f16* __restrict__ ctxT) {
    __shared__ f16 Ts[64][72];
    int bid = blockIdx.x;
    int tid = threadIdx.x;
    if (bid < 2048) {
        const int DD = Dc * Dc;
        int i = bid * 256 + tid;
        int stride = 2048 * 256;
        for (; i < 4 * DD; i += stride) {
            int sel = i / DD, j = i % DD;
            const float* s = (sel == 0) ? hW : (sel == 1) ? tW : (sel == 2) ? hcW : tcW;
            f16* d = (sel == 0) ? hWb : (sel == 1) ? tWb : (sel == 2) ? hcWb : tcWb;
            d[j] = (f16)s[j];
        }
    } else if (bid < 5120) {
        int gid = (bid - 2048) * 256 + tid;   // < 768*16*64
        int lane = gid & 63; int f = gid >> 6;
        int rt = f & 3; int s = (f >> 2) & 3; int c = f >> 4;
        int n_l = lane & 31, kg = lane >> 5;
        int r = rt * 32 + n_l;
        f16x8 v;
        if (r < Rc) {
            const float* src = clasW + (size_t)r * (Dc * 64) + c * 64 + s * 16 + kg * 8;
#pragma unroll
            for (int j = 0; j < 8; ++j) v[j] = (f16)src[j];
        } else {
#pragma unroll
            for (int j = 0; j < 8; ++j) v[j] = (f16)0.f;
        }
        ((f16x8*)Wp)[gid] = v;
    } else {
        int id = bid - 5120;           // ((b*8+lt)*12+dt)
        int dt = id % 12; int lt = (id / 12) % 8; int b = id / 96;
        int l0 = lt * 64, d0 = dt * 64;
        int r = tid >> 2, cg = tid & 3;
        const float* src = ctx + ((size_t)b * Lc + l0 + r) * Dc + d0 + cg * 16;
#pragma unroll
        for (int u = 0; u < 4; ++u) {
            float4 v = ((const float4*)src)[u];
            Ts[cg * 16 + u * 4 + 0][r] = (f16)v.x;
            Ts[cg * 16 + u * 4 + 1][r] = (f16)v.y;
            Ts[cg * 16 + u * 4 + 2][r] = (f16)v.z;
            Ts[cg * 16 + u * 4 + 3][r] = (f16)v.w;
        }
        __syncthreads();
        int dr = tid >> 2, seg = tid & 3;
        f16* dst = ctxT + ((size_t)b * Dc + d0 + dr) * Lc + l0 + seg * 16;
        f16x8 o0, o1;
#pragma unroll
        for (int j = 0; j < 8; ++j) { o0[j] = Ts[dr][seg * 16 + j]; o1[j] = Ts[dr][seg * 16 + 8 + j]; }
        *(f16x8*)dst = o0;
        *(f16x8*)(dst + 8) = o1;
    }
}

// ---------------- K1: mention = mm @ ctx via MFMA ----------------
__global__ __launch_bounds__(256) void k_mention_mfma(const float* __restrict__ mm,
                                                      const f16* __restrict__ ctxT,
                                                      float* __restrict__ mention) {
    __shared__ __align__(16) f16 As[2][64 * 64];
    __shared__ __align__(16) f16 Bs[2][64 * 64];
    int id = blockIdx.x;            // b*12+dt
    int dt = id % 12; int b = id / 12;
    int d0 = dt * 64;
    int tid = threadIdx.x;
    int w = tid >> 6, lane = tid & 63;
    int w_m = w & 1, w_n = w >> 1;
    int m_l = lane & 31, kg = lane >> 5;
    int r0 = tid >> 3, cc0 = tid & 7;
    int r1 = r0 + 32;
    int mr0 = (r0 < Mc) ? r0 : r0 - Mc;
    int mr1 = (r1 < Mc) ? r1 : r1 - Mc;
    f16x8 ar0, ar1, br0, br1;
    auto loadt = [&](int it) {
        int k0 = it * 64;
        const float* A0 = mm + ((size_t)b * Mc + mr0) * Lc + k0 + cc0 * 8;
        const float* A1 = mm + ((size_t)b * Mc + mr1) * Lc + k0 + cc0 * 8;
#pragma unroll
        for (int j = 0; j < 8; ++j) { ar0[j] = (f16)A0[j]; ar1[j] = (f16)A1[j]; }
        br0 = *(const f16x8*)(ctxT + ((size_t)b * Dc + d0 + r0) * Lc + k0 + cc0 * 8);
        br1 = *(const f16x8*)(ctxT + ((size_t)b * Dc + d0 + r1) * Lc + k0 + cc0 * 8);
    };
    auto writet = [&](int p) {
        ((f16x8*)As[p])[r0 * 8 + (cc0 ^ (r0 & 7))] = ar0;
        ((f16x8*)As[p])[r1 * 8 + (cc0 ^ (r1 & 7))] = ar1;
        ((f16x8*)Bs[p])[r0 * 8 + (cc0 ^ (r0 & 7))] = br0;
        ((f16x8*)Bs[p])[r1 * 8 + (cc0 ^ (r1 & 7))] = br1;
    };
    loadt(0); writet(0); loadt(1);
    f32x16 acc;
#pragma unroll
    for (int i = 0; i < 16; ++i) acc[i] = 0.f;
    int ar = w_m * 32 + m_l;
    int br = w_n * 32 + m_l;
    for (int it = 0; it < 8; ++it) {
        int p = it & 1;
        __syncthreads();
        if (it < 7) writet(p ^ 1);
        if (it < 6) loadt(it + 2);
#pragma unroll
        for (int s = 0; s < 4; ++s) {
            int ck = s * 2 + kg;
            f16x8 a = ((const f16x8*)As[p])[ar * 8 + (ck ^ (ar & 7))];
            f16x8 bv = ((const f16x8*)Bs[p])[br * 8 + (ck ^ (br & 7))];
            acc = __builtin_amdgcn_mfma_f32_32x32x16_f16(a, bv, acc, 0, 0, 0);
        }
    }
#pragma unroll
    for (int reg = 0; reg < 16; ++reg) {
        int row = (reg & 3) + 8 * (reg >> 2) + 4 * kg;
        int m = w_m * 32 + row;
        if (m < Mc) mention[((size_t)b * Mc + m) * Dc + d0 + w_n * 32 + m_l] = acc[reg];
    }
}

// ---------------- K2 fused: one pass over attention ----------------
__global__ __launch_bounds__(256) void k_attpass(const float* __restrict__ mm,
                                                 const float* __restrict__ emt,
                                                 const float* __restrict__ att,
                                                 float* __restrict__ tmpML,
                                                 float* __restrict__ eat) {
    __shared__ __align__(16) f16 Ss[96 * 64];
    __shared__ __align__(16) f16 attS[64 * 64];
    int id = blockIdx.x;
    int mt = id & 7; int bh = id >> 3;
    int b = bh / Hc, h = bh % Hc;
    int m0 = mt * 64;
    int tid = threadIdx.x;
    int w = tid >> 6, lane = tid & 63;
    int n_l = lane & 31, kg = lane >> 5;

    const float* ab = att + (size_t)bh * Lc * Lc + m0;
    int mRow = tid & 63, lg = tid >> 6;
    float pre[16];
#pragma unroll
    for (int q = 0; q < 16; ++q) pre[q] = ab[(size_t)(lg * 16 + q) * Lc + mRow];

    f32x16 acc[2];
#pragma unroll
    for (int nt = 0; nt < 2; ++nt)
#pragma unroll
        for (int i = 0; i < 16; ++i) acc[nt][i] = 0.f;

    for (int kc = 0; kc < 8; ++kc) {
        __syncthreads();
#pragma unroll
        for (int half = 0; half < 2; ++half) {
            int cc = lg * 2 + half;
            f16x8 v;
#pragma unroll
            for (int jj = 0; jj < 8; ++jj) v[jj] = (f16)pre[half * 8 + jj];
            ((f16x8*)attS)[mRow * 8 + (cc ^ (mRow & 7))] = v;
        }
#pragma unroll
        for (int k = 0; k < 3; ++k) {
            int idx = tid + k * 256;
            int row = idx >> 3, cc = idx & 7;
            f16x8 v;
            if (row < Mc) {
                const float* src = mm + ((size_t)b * Mc + row) * Lc + kc * 64 + cc * 8;
#pragma unroll
                for (int j = 0; j < 8; ++j) v[j] = (f16)src[j];
            } else if (row < 80) {
                const float* src = emt + ((size_t)b * Ec + row - Mc) * Lc + kc * 64 + cc * 8;
#pragma unroll
                for (int j = 0; j < 8; ++j) v[j] = (f16)src[j];
            } else {
#pragma unroll
                for (int j = 0; j < 8; ++j) v[j] = (f16)0.f;
            }
            ((f16x8*)Ss)[row * 8 + (cc ^ (row & 7))] = v;
        }
        if (kc < 7) {
#pragma unroll
            for (int q = 0; q < 16; ++q)
                pre[q] = ab[(size_t)((kc + 1) * 64 + lg * 16 + q) * Lc + mRow];
        }
        __syncthreads();
        if (w < 3) {
            int arow = w * 32 + n_l;
#pragma unroll
            for (int kk = 0; kk < 4; ++kk) {
                int cc = kk * 2 + kg;
                f16x8 a = ((const f16x8*)Ss)[arow * 8 + (cc ^ (arow & 7))];
#pragma unroll
                for (int nt = 0; nt < 2; ++nt) {
                    int bcol = nt * 32 + n_l;
                    f16x8 bb = ((const f16x8*)attS)[bcol * 8 + (cc ^ (bcol & 7))];
                    acc[nt] = __builtin_amdgcn_mfma_f32_32x32x16_f16(a, bb, acc[nt], 0, 0, 0);
                }
            }
        }
    }
    if (w < 3) {
#pragma unroll
        for (int nt = 0; nt < 2; ++nt)
#pragma unroll
            for (int reg = 0; reg < 16; ++reg) {
                int row = (reg & 3) + 8 * (reg >> 2) + 4 * kg;
                int rr = w * 32 + row;
                int col = m0 + nt * 32 + n_l;
                if (rr < Mc) {
                    atomicAdd(&tmpML[((size_t)b * Mc + rr) * Lc + col], acc[nt][reg]);
                } else if (rr < 80) {
                    eat[(((size_t)b * Hc + h) * Ec + (rr - Mc)) * Lc + col] = acc[nt][reg];
                }
            }
    }
}

// ---------------- K3 fused: mention_att (LDS only) + entity_att ----------------
__global__ __launch_bounds__(256) void k_ment_ent(const float* __restrict__ tmp,
                                                  const float* __restrict__ mm,
                                                  const float* __restrict__ em,
                                                  float* __restrict__ ea) {
    __shared__ float maS[Mc][12];
    int b = blockIdx.x >> 2, q = blockIdx.x & 3;
    int tid = threadIdx.x;
    for (int idx = tid; idx < Mc * 12; idx += 256) {
        int m = idx / 12, m2 = q * 12 + idx % 12;
        float acc = 0.f;
        const float* t = tmp + (size_t)(b * Mc + m) * Lc;
        const float* r = mm + (size_t)(b * Mc + m2) * Lc;
        for (int j = 0; j < Lc; ++j) acc += t[j] * r[j];
        maS[m][idx % 12] = acc;
    }
    __syncthreads();
    for (int idx = tid; idx < Ec * 12; idx += 256) {
        int e = idx / 12, m2q = idx % 12;
        float acc = 0.f;
        const float* emr = em + (size_t)(b * Ec + e) * Mc;
        for (int m = 0; m < Mc; ++m) acc += emr[m] * maS[m][m2q];
        ea[((size_t)b * Ec + e) * Mc + q * 12 + m2q] = acc;
    }
}

// ---------------- K5a: per-bp pair prep, barrier-free (1 wave per bp) ----------------
// hatN/tatN: normalized+masked f16 [bp][64] (rows 48..63 = 0). ca: normalized ctx_att.
__global__ __launch_bounds__(256) void k_pair(const int* __restrict__ hts,
                                              const float* __restrict__ em,
                                              const float* __restrict__ ea,
                                              const float* __restrict__ eat,
                                              f16* __restrict__ hatN, f16* __restrict__ tatN,
                                              float* __restrict__ ca) {
    int wv = threadIdx.x >> 6, lane = threadIdx.x & 63;
    int bp = blockIdx.x * 4 + wv;
    int b = bp >> 9;
    int hi = hts[bp * 2], ti = hts[bp * 2 + 1];
    float mask = (hi + ti != 0) ? 1.f : 0.f;
    float hat = 0.f, tat = 0.f;
    if (lane < Mc) {
        float hm = em[((size_t)(b * Ec + hi)) * Mc + lane];
        float tm = em[((size_t)(b * Ec + ti)) * Mc + lane];
        float eh = ea[((size_t)(b * Ec + hi)) * Mc + lane];
        float et = ea[((size_t)(b * Ec + ti)) * Mc + lane];
        hat = eh * tm * mask;   // h_att = entity_att[h_idx] * t_mask
        tat = et * hm * mask;   // t_att = entity_att[t_idx] * h_mask
    }
    float sh = hat, st = tat;
#pragma unroll
    for (int off = 1; off < 64; off <<= 1) { sh += __shfl_xor(sh, off); st += __shfl_xor(st, off); }
    float hnorm = 1.f / (sh + MINV);
    float tnorm = 1.f / (st + MINV);
    hatN[(size_t)bp * 64 + lane] = (f16)(hat * hnorm);
    tatN[(size_t)bp * 64 + lane] = (f16)(tat * tnorm);

    // ctx_att: prod[j] = sum_h eat[h][hi][j]*eat[h][ti][j], normalized by total
    const float* base = eat + (size_t)b * Hc * Ec * Lc;
    float prod[8];
    float tot = 0.f;
#pragma unroll
    for (int j8 = 0; j8 < 8; ++j8) {
        int j = j8 * 64 + lane;
        float a = 0.f;
#pragma unroll
        for (int h = 0; h < Hc; ++h)
            a += base[((size_t)h * Ec + hi) * Lc + j] * base[((size_t)h * Ec + ti) * Lc + j];
        prod[j8] = a;
        tot += a;
    }
#pragma unroll
    for (int off = 1; off < 64; off <<= 1) tot += __shfl_xor(tot, off);
    float inv = 1.f / (tot + MINV);
#pragma unroll
    for (int j8 = 0; j8 < 8; ++j8)
        ca[(size_t)bp * Lc + j8 * 64 + lane] = prod[j8] * inv;
}

// ---------------- K5b: h = tatN @ mention, t = hatN @ mention via MFMA (K=64 single tile) ----------------
__global__ __launch_bounds__(256) void k_ht_mfma(const f16* __restrict__ tatN, const f16* __restrict__ hatN,
                                                 const float* __restrict__ mention,
                                                 f16* __restrict__ hB, f16* __restrict__ tB) {
    __shared__ __align__(16) f16 At[64 * 64];   // tatN tile [p][k-chunks swizzled]
    __shared__ __align__(16) f16 Ah[64 * 64];   // hatN tile
    __shared__ __align__(16) f16 Bs[64 * 64];   // mention^T tile [d][m-chunks swizzled]
    int m0 = blockIdx.x * 64;    // p base
    int b = m0 >> 9;
    int d0 = blockIdx.y * 64;
    int tid = threadIdx.x;
    int w = tid >> 6, lane = tid & 63;
    int w_m = w & 1, w_n = w >> 1;
    int m_l = lane & 31, kg = lane >> 5;

    // stage A tiles (f16x8 chunks, XOR swizzle)
    for (int i = tid; i < 512; i += 256) {
        int p = i >> 3, c = i & 7;
        ((f16x8*)At)[p * 8 + (c ^ (p & 7))] = *(const f16x8*)(tatN + (size_t)(m0 + p) * 64 + c * 8);
        ((f16x8*)Ah)[p * 8 + (c ^ (p & 7))] = *(const f16x8*)(hatN + (size_t)(m0 + p) * 64 + c * 8);
    }
    // zero Bs, then fill transposed mention (rows m>=48 stay zero)
    for (int i = tid; i < 512; i += 256) {
        f16x8 z;
#pragma unroll
        for (int j = 0; j < 8; ++j) z[j] = (f16)0.f;
        ((f16x8*)Bs)[i] = z;
    }
    __syncthreads();
    if (tid < 192) {
        int m = tid >> 2, q = tid & 3;
        const float4* src = (const float4*)(mention + ((size_t)b * Mc + m) * Dc + d0 + q * 16);
#pragma unroll
        for (int u = 0; u < 4; ++u) {
            float4 v = src[u];
            int dl = q * 16 + u * 4;
#pragma unroll
            for (int x = 0; x < 4; ++x) {
                float vv = (x == 0) ? v.x : (x == 1) ? v.y : (x == 2) ? v.z : v.w;
                int d = dl + x;
                Bs[(d * 8 + ((m >> 3) ^ (d & 7))) * 8 + (m & 7)] = (f16)vv;
            }
        }
    }
    __syncthreads();

    f32x16 acch, acct;
#pragma unroll
    for (int i = 0; i < 16; ++i) { acch[i] = 0.f; acct[i] = 0.f; }
    int ar = w_m * 32 + m_l;
    int br = w_n * 32 + m_l;
#pragma unroll
    for (int s = 0; s < 4; ++s) {
        int ck = s * 2 + kg;
        f16x8 at_ = ((const f16x8*)At)[ar * 8 + (ck ^ (ar & 7))];
        f16x8 ah_ = ((const f16x8*)Ah)[ar * 8 + (ck ^ (ar & 7))];
        f16x8 bv = ((const f16x8*)Bs)[br * 8 + (ck ^ (br & 7))];
        acch = __builtin_amdgcn_mfma_f32_32x32x16_f16(at_, bv, acch, 0, 0, 0);   // h = t_att @ mention
        acct = __builtin_amdgcn_mfma_f32_32x32x16_f16(ah_, bv, acct, 0, 0, 0);   // t = h_att @ mention
    }
#pragma unroll
    for (int reg = 0; reg < 16; ++reg) {
        int row = (reg & 3) + 8 * (reg >> 2) + 4 * kg;
        int p = m0 + w_m * 32 + row;
        int d = d0 + w_n * 32 + m_l;
        hB[(size_t)p * Dc + d] = (f16)acch[reg];
        tB[(size_t)p * Dc + d] = (f16)acct[reg];
    }
}

// ---------------- K6: em_tok[b,e,l] normalized ----------------
__global__ __launch_bounds__(256) void k_emtok(const float* __restrict__ em,
                                               const float* __restrict__ mm,
                                               float* __restrict__ emt) {
    int be = blockIdx.x; int b = be / Ec;
    __shared__ float row[Mc];
    __shared__ float red[256];
    __shared__ float inv;
    int tid = threadIdx.x;
    if (tid < Mc) row[tid] = em[(size_t)be * Mc + tid];
    __syncthreads();
    float v0 = 0.f, v1 = 0.f;
    {
        const float* mb0 = mm + (size_t)b * Mc * Lc + tid;
        const float* mb1 = mm + (size_t)b * Mc * Lc + tid + 256;
        for (int m = 0; m < Mc; ++m) {
            v0 += row[m] * mb0[(size_t)m * Lc];
            v1 += row[m] * mb1[(size_t)m * Lc];
        }
    }
    red[tid] = v0 + v1;
    __syncthreads();
    for (int s = 128; s > 0; s >>= 1) { if (tid < s) red[tid] += red[tid + s]; __syncthreads(); }
    if (tid == 0) inv = 1.f / (red[0] + MINV);
    __syncthreads();
    emt[(size_t)be * Lc + tid] = v0 * inv;
    emt[(size_t)be * Lc + tid + 256] = v1 * inv;
}

// ---------------- K9: context_info via MFMA (f16) ----------------
__global__ __launch_bounds__(256) void k_ctxinfo_mfma(const int* __restrict__ hts,
                                                      const float* __restrict__ ca,
                                                      const f16* __restrict__ ctxT,
                                                      f16* __restrict__ ci) {
    __shared__ __align__(16) f16 As[2][64 * 64];
    __shared__ __align__(16) f16 Bs[2][64 * 64];
    __shared__ float maskS[64];
    int id = blockIdx.x;            // ((b*8+pt)*12+dt)
    int dt = id % 12; int pt = (id / 12) % 8; int b = id / 96;
    int p0 = pt * 64, d0 = dt * 64;
    int tid = threadIdx.x;
    int w = tid >> 6, lane = tid & 63;
    int w_m = w & 1, w_n = w >> 1;
    int m_l = lane & 31, kg = lane >> 5;
    int r0 = tid >> 3, cc0 = tid & 7;
    int r1 = r0 + 32;
    if (tid < 64) {
        int bp = b * Pc + p0 + tid;
        maskS[tid] = (hts[bp * 2] + hts[bp * 2 + 1] != 0) ? 1.f : 0.f;
    }
    f16x8 ar0, ar1, br0, br1;
    auto loadt = [&](int it) {
        int k0 = it * 64;
        const float* A0 = ca + (size_t)(b * Pc + p0 + r0) * Lc + k0 + cc0 * 8;
        const float* A1 = ca + (size_t)(b * Pc + p0 + r1) * Lc + k0 + cc0 * 8;
#pragma unroll
        for (int j = 0; j < 8; ++j) { ar0[j] = (f16)A0[j]; ar1[j] = (f16)A1[j]; }
        br0 = *(const f16x8*)(ctxT + (size_t)(b * Dc + d0 + r0) * Lc + k0 + cc0 * 8);
        br1 = *(const f16x8*)(ctxT + (size_t)(b * Dc + d0 + r1) * Lc + k0 + cc0 * 8);
    };
    auto writet = [&](int p) {
        ((f16x8*)As[p])[r0 * 8 + (cc0 ^ (r0 & 7))] = ar0;
        ((f16x8*)As[p])[r1 * 8 + (cc0 ^ (r1 & 7))] = ar1;
        ((f16x8*)Bs[p])[r0 * 8 + (cc0 ^ (r0 & 7))] = br0;
        ((f16x8*)Bs[p])[r1 * 8 + (cc0 ^ (r1 & 7))] = br1;
    };
    loadt(0); writet(0); loadt(1);
    f32x16 acc;
#pragma unroll
    for (int i = 0; i < 16; ++i) acc[i] = 0.f;
    int ar = w_m * 32 + m_l;
    int br = w_n * 32 + m_l;
    for (int it = 0; it < 8; ++it) {
        int p = it & 1;
        __syncthreads();
        if (it < 7) writet(p ^ 1);
        if (it < 6) loadt(it + 2);
#pragma unroll
        for (int s = 0; s < 4; ++s) {
            int ck = s * 2 + kg;
            f16x8 a = ((const f16x8*)As[p])[ar * 8 + (ck ^ (ar & 7))];
            f16x8 bv = ((const f16x8*)Bs[p])[br * 8 + (ck ^ (br & 7))];
            acc = __builtin_amdgcn_mfma_f32_32x32x16_f16(a, bv, acc, 0, 0, 0);
        }
    }
#pragma unroll
    for (int reg = 0; reg < 16; ++reg) {
        int row = (reg & 3) + 8 * (reg >> 2) + 4 * kg;
        int p = p0 + w_m * 32 + row;
        int d = d0 + w_n * 32 + m_l;
        ci[(size_t)(b * Pc + p) * Dc + d] = (f16)(acc[reg] * maskS[w_m * 32 + row]);
    }
}

// ---------------- K10: MFMA proj merged (z=2), f16 ----------------
__global__ __launch_bounds__(256) void k_proj_mfma(const f16* __restrict__ Xh, const f16* __restrict__ Wh,
                                                   const float* __restrict__ bh,
                                                   const f16* __restrict__ Xt, const f16* __restrict__ Wt,
                                                   const float* __restrict__ bt,
                                                   const f16* __restrict__ Xc, const f16* __restrict__ Whc,
                                                   const float* __restrict__ bhc,
                                                   const f16* __restrict__ Wtc, const float* __restrict__ btc,
                                                   f16* __restrict__ outh, f16* __restrict__ outt) {
    __shared__ __align__(16) f16 Xs[2][64 * 64];
    __shared__ __align__(16) f16 Ws[2][64 * 64];
    int z = blockIdx.z;
    const f16* X1 = z ? Xt : Xh;
    const f16* W1 = z ? Wt : Wh;
    const float* b1 = z ? bt : bh;
    const f16* W2 = z ? Wtc : Whc;
    const float* b2 = z ? btc : bhc;
    f16* outp = z ? outt : outh;
    int m0 = blockIdx.x * 64, n0 = blockIdx.y * 64;
    int tid = threadIdx.x;
    int w = tid >> 6, lane = tid & 63;
    int w_m = w & 1, w_n = w >> 1;
    int m_l = lane & 31, kg = lane >> 5;
    const f16* Xarr[2] = {X1, Xc};
    const f16* Warr[2] = {W1, W2};
    int r0 = tid >> 3, cc0 = tid & 7;
    int r1 = r0 + 32;
    f16x8 xr0, xr1, wr0, wr1;
    auto loadt = [&](int it) {
        int src = it / 12; int k0 = (it % 12) * 64;
        const f16* X = Xarr[src]; const f16* W = Warr[src];
        xr0 = *(const f16x8*)(X + (size_t)(m0 + r0) * Dc + k0 + cc0 * 8);
        xr1 = *(const f16x8*)(X + (size_t)(m0 + r1) * Dc + k0 + cc0 * 8);
        wr0 = *(const f16x8*)(W + (size_t)(n0 + r0) * Dc + k0 + cc0 * 8);
        wr1 = *(const f16x8*)(W + (size_t)(n0 + r1) * Dc + k0 + cc0 * 8);
    };
    auto writet = [&](int p) {
        ((f16x8*)Xs[p])[r0 * 8 + (cc0 ^ (r0 & 7))] = xr0;
        ((f16x8*)Xs[p])[r1 * 8 + (cc0 ^ (r1 & 7))] = xr1;
        ((f16x8*)Ws[p])[r0 * 8 + (cc0 ^ (r0 & 7))] = wr0;
        ((f16x8*)Ws[p])[r1 * 8 + (cc0 ^ (r1 & 7))] = wr1;
    };
    loadt(0); writet(0); loadt(1);
    f32x16 acc;
#pragma unroll
    for (int i = 0; i < 16; ++i) acc[i] = 0.f;
    int ar = w_m * 32 + m_l;
    int br = w_n * 32 + m_l;
    for (int it = 0; it < 24; ++it) {
        int p = it & 1;
        __syncthreads();
        if (it < 23) writet(p ^ 1);
        if (it < 22) loadt(it + 2);
#pragma unroll
        for (int s = 0; s < 4; ++s) {
            int ck = s * 2 + kg;
            f16x8 a = ((const f16x8*)Xs[p])[ar * 8 + (ck ^ (ar & 7))];
            f16x8 b = ((const f16x8*)Ws[p])[br * 8 + (ck ^ (br & 7))];
            acc = __builtin_amdgcn_mfma_f32_32x32x16_f16(a, b, acc, 0, 0, 0);
        }
    }
#pragma unroll
    for (int reg = 0; reg < 16; ++reg) {
        int row = (reg & 3) + 8 * (reg >> 2) + 4 * kg;
        int m = m0 + w_m * 32 + row;
        int n = n0 + w_n * 32 + m_l;
        float v = tanhf(acc[reg] + b1[n] + b2[n]);
        outp[(size_t)m * Dc + n] = (f16)v;
    }
}

// ---------------- K11b v6: group bilinear, partials via plain stores (no atomics) ----------------
__global__ __launch_bounds__(256, 3) void k_bilin6(const f16* __restrict__ hF, const f16* __restrict__ tF,
                                                   const f16* __restrict__ Wp, f16* __restrict__ partial) {
    __shared__ __align__(16) f16 tS[128 * 64];
    __shared__ f16 hS[128 * 17];
    int id = blockIdx.x;
    int tile = id / 48;
    int slice = id % 48;
    int bp0 = tile * 128;
    int tid = threadIdx.x;
    int w = tid >> 6, lane = tid & 63;
    int w_m = w & 1, w_r = w >> 1;
    int m_l = lane & 31, kg = lane >> 5;
    int c0 = slice * 16;
    int n = c0 >> 6;

    for (int idx = tid; idx < 128 * 16; idx += 256) {
        int bp = idx >> 4, i = idx & 15;
        hS[bp * 17 + i] = hF[(size_t)(bp0 + bp) * Dc + c0 + i];
    }
    for (int idx = tid; idx < 128 * 8; idx += 256) {
        int bp = idx >> 3, cc = idx & 7;
        f16x8 tv = *(const f16x8*)(tF + (size_t)(bp0 + bp) * Dc + n * 64 + cc * 8);
        ((f16x8*)tS)[bp * 8 + (cc ^ (bp & 7))] = tv;
    }
    __syncthreads();

    f32x16 acc[2][2];
#pragma unroll
    for (int mt = 0; mt < 2; ++mt)
#pragma unroll
        for (int rt = 0; rt < 2; ++rt)
#pragma unroll
            for (int i = 0; i < 16; ++i) acc[mt][rt][i] = 0.f;

    int rowA = w_m * 64 + m_l;
    int rowB = rowA + 32;
    const f16x8* WpB = (const f16x8*)Wp;

    for (int ii = 0; ii < 16; ++ii) {
        int cc = c0 + ii;
        const f16x8* wpb = WpB + (size_t)cc * 16 * 64 + lane;
        f16x8 Bf[8];
#pragma unroll
        for (int s = 0; s < 4; ++s) {
            Bf[s * 2 + 0] = wpb[(s * 4 + 2 * w_r + 0) * 64];
            Bf[s * 2 + 1] = wpb[(s * 4 + 2 * w_r + 1) * 64];
        }
        f16 hv0 = hS[rowA * 17 + ii];
        f16 hv1 = hS[rowB * 17 + ii];
#pragma unroll
        for (int s = 0; s < 4; ++s) {
            int ck = s * 2 + kg;
            f16x8 tv0 = ((const f16x8*)tS)[rowA * 8 + (ck ^ (rowA & 7))];
            f16x8 tv1 = ((const f16x8*)tS)[rowB * 8 + (ck ^ (rowB & 7))];
            f16x8 a0 = tv0 * hv0;
            f16x8 a1 = tv1 * hv1;
            acc[0][0] = __builtin_amdgcn_mfma_f32_32x32x16_f16(a0, Bf[s * 2 + 0], acc[0][0], 0, 0, 0);
            acc[1][0] = __builtin_amdgcn_mfma_f32_32x32x16_f16(a1, Bf[s * 2 + 0], acc[1][0], 0, 0, 0);
            acc[0][1] = __builtin_amdgcn_mfma_f32_32x32x16_f16(a0, Bf[s * 2 + 1], acc[0][1], 0, 0, 0);
            acc[1][1] = __builtin_amdgcn_mfma_f32_32x32x16_f16(a1, Bf[s * 2 + 1], acc[1][1], 0, 0, 0);
        }
    }

    f16* pbase = partial + (size_t)slice * (2048 * 128);
#pragma unroll
    for (int rt = 0; rt < 2; ++rt) {
        int r = (w_r * 2 + rt) * 32 + m_l;
#pragma unroll
        for (int mt = 0; mt < 2; ++mt)
#pragma unroll
            for (int reg = 0; reg < 16; ++reg) {
                int row = (reg & 3) + 8 * (reg >> 2) + 4 * kg;
                int bp = bp0 + w_m * 64 + mt * 32 + row;
                pbase[(size_t)bp * 128 + r] = (f16)acc[mt][rt][reg];
            }
    }
}

// ---------------- K12: reduce partials + bias -> out ----------------
__global__ __launch_bounds__(256) void k_reduce(const f16* __restrict__ partial,
                                                const float* __restrict__ cb,
                                                float* __restrict__ out) {
    int idx = blockIdx.x * 256 + threadIdx.x;   // < 2048*32 (f16x4 chunks)
    int bp = idx >> 5, c = idx & 31;
    const f16x4* p = (const f16x4*)partial + idx;
    float a0 = 0.f, a1 = 0.f, a2 = 0.f, a3 = 0.f;
#pragma unroll
    for (int s = 0; s < 48; ++s) {
        f16x4 v = p[(size_t)s * (2048 * 32)];
        a0 += (float)v[0]; a1 += (float)v[1]; a2 += (float)v[2]; a3 += (float)v[3];
    }
    int rb = c * 4;
    float* ob = out + (size_t)bp * Rc;
    if (rb + 0 < Rc) ob[rb + 0] = a0 + cb[rb + 0];
    if (rb + 1 < Rc) ob[rb + 1] = a1 + cb[rb + 1];
    if (rb + 2 < Rc) ob[rb + 2] = a2 + cb[rb + 2];
    if (rb + 3 < Rc) ob[rb + 3] = a3 + cb[rb + 3];
}

extern "C" void kernel_launch(void* const* d_in, const int* in_sizes, int n_in,
                              void* d_out, int out_size, void* d_ws, size_t ws_size,
                              hipStream_t stream) {
    const float* context   = (const float*)d_in[0];
    const float* attention = (const float*)d_in[1];
    const float* mm        = (const float*)d_in[2];
    const float* em        = (const float*)d_in[3];
    const int*   hts       = (const int*)d_in[4];
    const float* hW        = (const float*)d_in[5];
    const float* hb        = (const float*)d_in[6];
    const float* tW        = (const float*)d_in[7];
    const float* tb        = (const float*)d_in[8];
    const float* hcW       = (const float*)d_in[9];
    const float* hcb       = (const float*)d_in[10];
    const float* tcW       = (const float*)d_in[11];
    const float* tcb       = (const float*)d_in[12];
    const float* clasW     = (const float*)d_in[13];
    const float* clasb     = (const float*)d_in[14];
    float* out = (float*)d_out;

    char* wsb = (char*)d_ws;
    auto alloc = [&](size_t bytes) { char* p = wsb; wsb += (bytes + 255) & ~(size_t)255; return p; };
    float* mention     = (float*)alloc((size_t)Bc * Mc * Dc * 4);
    float* tmpML       = (float*)alloc((size_t)Bc * Mc * Lc * 4);
    float* entity_att  = (float*)alloc((size_t)Bc * Ec * Mc * 4);
    float* em_tok      = (float*)alloc((size_t)Bc * Ec * Lc * 4);
    float* ent_att     = (float*)alloc((size_t)Bc * Hc * Ec * Lc * 4);
    float* ctx_att     = (float*)alloc((size_t)Bc * Pc * Lc * 4);
    f16* hatN    = (f16*)alloc((size_t)Bc * Pc * 64 * 2);
    f16* tatN    = (f16*)alloc((size_t)Bc * Pc * 64 * 2);
    f16* h_buf   = (f16*)alloc((size_t)Bc * Pc * Dc * 2);
    f16* t_buf   = (f16*)alloc((size_t)Bc * Pc * Dc * 2);
    f16* ctxinfo = (f16*)alloc((size_t)Bc * Pc * Dc * 2);
    f16* h_fin   = (f16*)alloc((size_t)Bc * Pc * Dc * 2);
    f16* t_fin   = (f16*)alloc((size_t)Bc * Pc * Dc * 2);
    f16* hWb     = (f16*)alloc((size_t)Dc * Dc * 2);
    f16* tWb     = (f16*)alloc((size_t)Dc * Dc * 2);
    f16* hcWb    = (f16*)alloc((size_t)Dc * Dc * 2);
    f16* tcWb    = (f16*)alloc((size_t)Dc * Dc * 2);
    f16* ctxT    = (f16*)alloc((size_t)Bc * Dc * Lc * 2);
    f16* Wp      = (f16*)alloc((size_t)768 * 16 * 64 * 8 * 2);
    f16* partial = (f16*)alloc((size_t)48 * 2048 * 128 * 2);

    hipMemsetAsync(tmpML, 0, (size_t)Bc * Mc * Lc * 4, stream);
    k_prep<<<dim3(5504), dim3(256), 0, stream>>>(hW, tW, hcW, tcW, hWb, tWb, hcWb, tcWb,
                                                 clasW, Wp, context, ctxT);
    k_emtok<<<dim3(Bc * Ec), dim3(256), 0, stream>>>(em, mm, em_tok);
    k_attpass<<<dim3(Bc * Hc * 8), dim3(256), 0, stream>>>(mm, em_tok, attention, tmpML, ent_att);
    k_mention_mfma<<<dim3(Bc * 12), dim3(256), 0, stream>>>(mm, ctxT, mention);
    k_ment_ent<<<dim3(Bc * 4), dim3(256), 0, stream>>>(tmpML, mm, em, entity_att);
    k_pair<<<dim3(Bc * Pc / 4), dim3(256), 0, stream>>>(hts, em, entity_att, ent_att, hatN, tatN, ctx_att);
    k_ht_mfma<<<dim3(32, 12), dim3(256), 0, stream>>>(tatN, hatN, mention, h_buf, t_buf);
    k_ctxinfo_mfma<<<dim3(384), dim3(256), 0, stream>>>(hts, ctx_att, ctxT, ctxinfo);
    k_proj_mfma<<<dim3(32, 12, 2), dim3(256), 0, stream>>>(h_buf, hWb, hb, t_buf, tWb, tb,
                                                           ctxinfo, hcWb, hcb, tcWb, tcb, h_fin, t_fin);
    k_bilin6<<<dim3(768), dim3(256), 0, stream>>>(h_fin, t_fin, Wp, partial);
    k_reduce<<<dim3(256), dim3(256), 0, stream>>>(partial, clasb, out);
}